// Round 1
// baseline (921.192 us; speedup 1.0000x reference)
//
#include <hip/hip_runtime.h>
#include <cstdint>
#include <cfloat>

#define F 16
#define B 4096
#define D 256
#define K 1024

typedef __attribute__((ext_vector_type(8))) _Float16 f16x8;
typedef __attribute__((ext_vector_type(4))) float f32x4;

// ---- workspace layout (bytes) ----
#define XH_OFF   0u            // F*B*D fp16 = 33554432
#define WHT_OFF  33554432u     // F*K*D fp16 transposed [f][k][d] = 8388608
#define WT_OFF   41943040u     // F*K*D fp32 transposed = 16777216
#define WSQ_OFF  58720256u     // F*K fp32 = 65536
#define TOP3_OFF 58785792u     // F*B * 32B {v1,i1,v2,i2,v3,i3,_,_} = 2 MB
#define LOSS_OFF 60882944u

#define THR 0.012f             // refine ambiguity threshold (~13 sigma of fp16 GEMM err)

__device__ __forceinline__ void async_load16(const void* g, void* l) {
    __builtin_amdgcn_global_load_lds(
        (const __attribute__((address_space(1))) void*)g,
        (__attribute__((address_space(3))) void*)l, 16, 0, 0);
}

// merge two sorted top-3 lists (value asc, index tie-break asc) -> top-3
__device__ __forceinline__ void merge3(
        float& v1, int& i1, float& v2, int& i2, float& v3, int& i3,
        float w1, int j1, float w2, int j2, float w3, int j3)
{
    bool s = (w1 < v1) || (w1 == v1 && j1 < i1);
    float A1 = s ? w1 : v1; int A1i = s ? j1 : i1;
    float A2 = s ? w2 : v2; int A2i = s ? j2 : i2;
    float A3 = s ? w3 : v3; int A3i = s ? j3 : i3;
    float B1 = s ? v1 : w1; int B1i = s ? i1 : j1;
    float B2 = s ? v2 : w2; int B2i = s ? i2 : j2;
    // r1 = A1. remaining candidates: A2,A3 vs B1,B2
    bool t = (B1 < A2) || (B1 == A2 && B1i < A2i);
    float r2 = t ? B1 : A2; int r2i = t ? B1i : A2i;
    float c1 = t ? A2 : A3; int c1i = t ? A2i : A3i;
    float c2 = t ? B2 : B1; int c2i = t ? B2i : B1i;
    bool u = (c2 < c1) || (c2 == c1 && c2i < c1i);
    float r3 = u ? c2 : c1; int r3i = u ? c2i : c1i;
    v1 = A1; i1 = A1i; v2 = r2; i2 = r2i; v3 = r3; i3 = r3i;
}

// ---------------- init: zero wsq + loss ----------------
__global__ void init_kernel(float* __restrict__ wsq, double* __restrict__ lossAcc) {
    int i = blockIdx.x * 256 + threadIdx.x;
    if (i < F * K) wsq[i] = 0.f;
    if (i == 0) *lossAcc = 0.0;
}

// ---------------- x -> fp16 ----------------
__global__ void split_x(const float* __restrict__ x, ushort* __restrict__ xh) {
    int i = (blockIdx.x * 256 + threadIdx.x) * 4;
    float4 v = *(const float4*)(x + i);
    ushort4 h;
#pragma unroll
    for (int j = 0; j < 4; ++j) {
        _Float16 hv = (_Float16)(((const float*)&v)[j]);
        ((ushort*)&h)[j] = *(ushort*)&hv;
    }
    *(ushort4*)(xh + i) = h;
}

// ------- transpose w -> wt fp32 [f][k][d] + fp16 + fused ||w_k||^2 -------
__global__ void transpose_split_w(const float* __restrict__ w, float* __restrict__ wt,
                                  ushort* __restrict__ whT, float* __restrict__ wsq) {
    __shared__ float sd[32][33];
    int f  = blockIdx.z;
    int k0 = blockIdx.x * 32;
    int d0 = blockIdx.y * 32;
    const float* wf = w + (size_t)f * D * K;
    size_t obase = (size_t)f * K * D;
    int tx = threadIdx.x, ty = threadIdx.y;
#pragma unroll
    for (int i = 0; i < 4; ++i) {
        int d = ty + i * 8;
        sd[d][tx] = wf[(size_t)(d0 + d) * K + (k0 + tx)];
    }
    __syncthreads();
#pragma unroll
    for (int i = 0; i < 4; ++i) {
        int k = ty + i * 8;
        float v = sd[tx][k];
        size_t o = obase + (size_t)(k0 + k) * D + (d0 + tx);
        wt[o] = v;
        _Float16 hv = (_Float16)v;
        whT[o] = *(ushort*)&hv;
        float p = v * v;
#pragma unroll
        for (int off = 1; off < 32; off <<= 1) p += __shfl_xor(p, off);
        if (tx == 0) atomicAdd(&wsq[f * K + k0 + k], p);
    }
}

// ---------------- MFMA fp16 1-pass GEMM + top-3 ----------------
// A (64 rows, full D) resident in LDS seg-major; W streamed 8 KB/stage.
// LDS ushort units: A [0,16384)  W [16384,20480)   -> 40 KiB
__global__ __launch_bounds__(512, 6) void gemm_mfma_top3(
        const ushort* __restrict__ xh, const ushort* __restrict__ whT,
        const float* __restrict__ wsq, float4* __restrict__ top3v)
{
    __shared__ ushort lds[20480];   // 40 KiB
    const int bid  = blockIdx.x;
    const int f    = bid >> 6;             // 64 consecutive blocks share f (W L2-hot)
    const int m0   = (bid & 63) * 64;
    const int tid  = threadIdx.x;
    const int lane = tid & 63;
    const int wave = tid >> 6;             // 0..7
    const int mw   = wave >> 2;            // 0..1 : 32-row half
    const int nw   = wave & 3;             // 0..3 : 32-col quarter of the 128-chunk
    const int quad = lane >> 4, l15 = lane & 15;

    const ushort* xhb = xh  + ((size_t)f * B + m0) * D;
    const ushort* whb = whT + (size_t)f * K * D;

    // ---- prologue: stage A seg-major [seg 0..31][row 0..63][8]
#pragma unroll
    for (int i = 0; i < 4; ++i) {
        int linear = i * 512 + tid;        // 0..2047 16B-slots
        int s = linear >> 6, row = linear & 63;
        async_load16(xhb + (size_t)row * D + s * 8, lds + linear * 8);
    }

    float v1[8], v2[8];
    int   i1[8], i2[8];
#pragma unroll
    for (int s = 0; s < 8; ++s) {
        v1[s] = FLT_MAX; v2[s] = FLT_MAX; i1[s] = 0x7fffffff; i2[s] = 0x7fffffff;
    }

    // W staging indices (constant per thread)
    const int wq_ = tid >> 7;              // d-seg 0..3
    const int wn_ = tid & 127;             // col 0..127

    for (int n0 = 0; n0 < K; n0 += 128) {
        f32x4 acc[2][2];
#pragma unroll
        for (int mt = 0; mt < 2; ++mt)
#pragma unroll
            for (int nt = 0; nt < 2; ++nt)
                acc[mt][nt] = (f32x4){0.f, 0.f, 0.f, 0.f};

        const ushort* wh_n = whb + (size_t)(n0 + wn_) * D + wq_ * 8;

        for (int d0 = 0; d0 < D; d0 += 32) {
            __syncthreads();   // previous stage's reads done; buffer reusable
            async_load16(wh_n + d0, lds + 16384 + tid * 8);
            __syncthreads();   // loads visible (barrier drains vmcnt)

            const int sA = (d0 >> 3) + quad;
            f16x8 ah[2];
#pragma unroll
            for (int mt = 0; mt < 2; ++mt)
                ah[mt] = *(const f16x8*)(lds + sA * 512 + (mw * 32 + mt * 16 + l15) * 8);
#pragma unroll
            for (int nt = 0; nt < 2; ++nt) {
                f16x8 bh = *(const f16x8*)(lds + 16384 + quad * 1024 + (nw * 32 + nt * 16 + l15) * 8);
#pragma unroll
                for (int mt = 0; mt < 2; ++mt)
                    acc[mt][nt] = __builtin_amdgcn_mfma_f32_16x16x32_f16(ah[mt], bh, acc[mt][nt], 0, 0, 0);
            }
        }

        // epilogue: fold 128-column chunk into per-lane top-2
#pragma unroll
        for (int nt = 0; nt < 2; ++nt) {
            int ng = n0 + nw * 32 + nt * 16 + l15;
            float wq = wsq[f * K + ng];
#pragma unroll
            for (int mt = 0; mt < 2; ++mt) {
#pragma unroll
                for (int r = 0; r < 4; ++r) {
                    int s = mt * 4 + r;
                    float sc = fmaf(-2.f, acc[mt][nt][r], wq);
                    if (sc < v1[s]) { v2[s] = v1[s]; i2[s] = i1[s]; v1[s] = sc; i1[s] = ng; }
                    else if (sc < v2[s]) { v2[s] = sc; i2[s] = ng; }
                }
            }
        }
    }

    // extend to top-3 and butterfly-merge among the 16 l15 lanes (fixed quad)
    float v3[8]; int i3[8];
#pragma unroll
    for (int s = 0; s < 8; ++s) { v3[s] = FLT_MAX; i3[s] = 0x7fffffff; }
#pragma unroll
    for (int s = 0; s < 8; ++s) {
#pragma unroll
        for (int off = 1; off < 16; off <<= 1) {
            float w1 = __shfl_xor(v1[s], off); int j1 = __shfl_xor(i1[s], off);
            float w2 = __shfl_xor(v2[s], off); int j2 = __shfl_xor(i2[s], off);
            float w3 = __shfl_xor(v3[s], off); int j3 = __shfl_xor(i3[s], off);
            merge3(v1[s], i1[s], v2[s], i2[s], v3[s], i3[s], w1, j1, w2, j2, w3, j3);
        }
    }

    // cross-wave (nw 0..3) merge via LDS: [64 rows][4 nw][2 float4]
    __syncthreads();                       // all compute/LDS reads done
    float4* mrg = (float4*)lds;
    if (l15 == 0) {
#pragma unroll
        for (int mt = 0; mt < 2; ++mt)
#pragma unroll
            for (int r = 0; r < 4; ++r) {
                int s = mt * 4 + r;
                int rl = mw * 32 + mt * 16 + quad * 4 + r;
                mrg[(rl * 4 + nw) * 2 + 0] = make_float4(v1[s], __int_as_float(i1[s]),
                                                         v2[s], __int_as_float(i2[s]));
                mrg[(rl * 4 + nw) * 2 + 1] = make_float4(v3[s], __int_as_float(i3[s]), 0.f, 0.f);
            }
    }
    __syncthreads();
    if (nw == 0 && l15 == 0) {
#pragma unroll
        for (int mt = 0; mt < 2; ++mt)
#pragma unroll
            for (int r = 0; r < 4; ++r) {
                int rl = mw * 32 + mt * 16 + quad * 4 + r;
                float4 ta = mrg[(rl * 4 + 0) * 2 + 0];
                float4 tb = mrg[(rl * 4 + 0) * 2 + 1];
                float bv1 = ta.x, bv2 = ta.z, bv3 = tb.x;
                int   bi1 = __float_as_int(ta.y), bi2 = __float_as_int(ta.w),
                      bi3 = __float_as_int(tb.y);
#pragma unroll
                for (int q = 1; q < 4; ++q) {
                    float4 oa = mrg[(rl * 4 + q) * 2 + 0];
                    float4 ob = mrg[(rl * 4 + q) * 2 + 1];
                    merge3(bv1, bi1, bv2, bi2, bv3, bi3,
                           oa.x, __float_as_int(oa.y), oa.z, __float_as_int(oa.w),
                           ob.x, __float_as_int(ob.y));
                }
                size_t orow = (size_t)f * B + m0 + rl;
                top3v[orow * 2 + 0] = make_float4(bv1, __int_as_float(bi1),
                                                  bv2, __int_as_float(bi2));
                top3v[orow * 2 + 1] = make_float4(bv3, __int_as_float(bi3), 0.f, 0.f);
            }
    }
}

// -------- fp64 refine + gather + loss; exact-check c2/c3 when gap < THR --------
__global__ __launch_bounds__(256) void refine_gather(
        const float* __restrict__ x, const float* __restrict__ wt,
        const float4* __restrict__ top3v, float* __restrict__ out,
        double* __restrict__ lossAcc) {
    __shared__ double lpart[4];
    int tid  = threadIdx.x;
    int wv   = tid >> 6;
    int lane = tid & 63;
    double lsum = 0.0;
    for (int it = 0; it < 16; ++it) {
        size_t row = ((size_t)blockIdx.x * 16 + it) * 4 + wv;
        int f = (int)(row >> 12);
        float4 ta = top3v[row * 2 + 0];
        float4 tb = top3v[row * 2 + 1];
        int c1 = __float_as_int(ta.y);
        const float* xr = x + row * D;
        float4 xv = ((const float4*)xr)[lane];

        const float* w1 = wt + ((size_t)f * K + c1) * D;
        float4 a  = ((const float4*)w1)[lane];
        double s1 = 0.0;
#pragma unroll
        for (int j = 0; j < 4; ++j) {
            double d1 = (double)((const float*)&xv)[j] - (double)((const float*)&a)[j];
            s1 = fma(d1, d1, s1);
        }
#pragma unroll
        for (int off = 1; off < 64; off <<= 1) s1 += __shfl_xor(s1, off);

        float4 q = a;
        double sel = s1;
        int selc = c1;

        if (ta.z - ta.x < THR) {   // candidate 2 ambiguous (wave-uniform)
            int c2 = __float_as_int(ta.w);
            const float* w2 = wt + ((size_t)f * K + c2) * D;
            float4 b = ((const float4*)w2)[lane];
            double s2 = 0.0;
#pragma unroll
            for (int j = 0; j < 4; ++j) {
                double d2 = (double)((const float*)&xv)[j] - (double)((const float*)&b)[j];
                s2 = fma(d2, d2, s2);
            }
#pragma unroll
            for (int off = 1; off < 64; off <<= 1) s2 += __shfl_xor(s2, off);
            if ((s2 < sel) || (s2 == sel && c2 < selc)) { q = b; sel = s2; selc = c2; }
        }
        if (tb.x - ta.x < THR) {   // candidate 3 ambiguous (wave-uniform)
            int c3 = __float_as_int(tb.y);
            const float* w3 = wt + ((size_t)f * K + c3) * D;
            float4 b = ((const float4*)w3)[lane];
            double s3 = 0.0;
#pragma unroll
            for (int j = 0; j < 4; ++j) {
                double d3 = (double)((const float*)&xv)[j] - (double)((const float*)&b)[j];
                s3 = fma(d3, d3, s3);
            }
#pragma unroll
            for (int off = 1; off < 64; off <<= 1) s3 += __shfl_xor(s3, off);
            if ((s3 < sel) || (s3 == sel && c3 < selc)) { q = b; sel = s3; selc = c3; }
        }
        ((float4*)(out + row * D))[lane] = q;
        if (lane == 0) lsum += sel;
    }
    if (lane == 0) lpart[wv] = lsum;
    __syncthreads();
    if (tid == 0) {
        double tsum = lpart[0] + lpart[1] + lpart[2] + lpart[3];
        atomicAdd(lossAcc, tsum);
    }
}

__global__ void finish_loss(const double* __restrict__ lossAcc,
                            float* __restrict__ out_loss) {
    if (threadIdx.x == 0)
        *out_loss = (float)(0.25 * (*lossAcc) / ((double)F * (double)B * (double)D));
}

extern "C" void kernel_launch(void* const* d_in, const int* in_sizes, int n_in,
                              void* d_out, int out_size, void* d_ws, size_t ws_size,
                              hipStream_t stream) {
    const float* x = (const float*)d_in[0];   // [F,B,D]
    const float* w = (const float*)d_in[1];   // [F,D,K]
    float* out = (float*)d_out;

    ushort* xh    = (ushort*)((char*)d_ws + XH_OFF);
    ushort* whT   = (ushort*)((char*)d_ws + WHT_OFF);
    float*  wt    = (float*)((char*)d_ws + WT_OFF);
    float*  wsq   = (float*)((char*)d_ws + WSQ_OFF);
    float4* top3v = (float4*)((char*)d_ws + TOP3_OFF);
    double* lossAcc = (double*)((char*)d_ws + LOSS_OFF);

    init_kernel<<<dim3(64), 256, 0, stream>>>(wsq, lossAcc);
    split_x<<<dim3(F * B * D / 1024), 256, 0, stream>>>(x, xh);
    transpose_split_w<<<dim3(K / 32, D / 32, F), dim3(32, 8), 0, stream>>>(w, wt, whT, wsq);
    gemm_mfma_top3<<<dim3((B / 64) * F), 512, 0, stream>>>(xh, whT, wsq, top3v);
    refine_gather<<<dim3(F * B / 64), 256, 0, stream>>>(x, wt, top3v, out, lossAcc);
    finish_loss<<<1, 64, 0, stream>>>(lossAcc, out + (size_t)F * B * D);
}

// Round 2
// 320.527 us; speedup vs baseline: 2.8740x; 2.8740x over previous
//
#include <hip/hip_runtime.h>
#include <cstdint>
#include <cfloat>

#define F 16
#define B 4096
#define D 256
#define K 1024

typedef __attribute__((ext_vector_type(8))) _Float16 f16x8;
typedef __attribute__((ext_vector_type(4))) float f32x4;

// ---- workspace layout (bytes) ----
#define XH_OFF   0u            // F*B*D fp16 = 33554432
#define WHT_OFF  33554432u     // F*K*D fp16 transposed [f][k][d] = 8388608
#define WT_OFF   41943040u     // F*K*D fp32 transposed = 16777216
#define WSQ_OFF  58720256u     // F*K fp32 = 65536
#define TOP3_OFF 58785792u     // F*B * 32B {v1,i1,v2,i2,v3,i3,_,_} = 2 MB
#define LOSS_OFF 60882944u

#define THR 0.012f             // refine ambiguity threshold (~13 sigma of fp16 GEMM err)

__device__ __forceinline__ void async_load16(const void* g, void* l) {
    __builtin_amdgcn_global_load_lds(
        (const __attribute__((address_space(1))) void*)g,
        (__attribute__((address_space(3))) void*)l, 16, 0, 0);
}

// merge two sorted top-3 lists (value asc, index tie-break asc) -> top-3
__device__ __forceinline__ void merge3(
        float& v1, int& i1, float& v2, int& i2, float& v3, int& i3,
        float w1, int j1, float w2, int j2, float w3, int j3)
{
    bool s = (w1 < v1) || (w1 == v1 && j1 < i1);
    float A1 = s ? w1 : v1; int A1i = s ? j1 : i1;
    float A2 = s ? w2 : v2; int A2i = s ? j2 : i2;
    float A3 = s ? w3 : v3; int A3i = s ? j3 : i3;
    float B1 = s ? v1 : w1; int B1i = s ? i1 : j1;
    float B2 = s ? v2 : w2; int B2i = s ? i2 : j2;
    // r1 = A1. remaining candidates: A2,A3 vs B1,B2
    bool t = (B1 < A2) || (B1 == A2 && B1i < A2i);
    float r2 = t ? B1 : A2; int r2i = t ? B1i : A2i;
    float c1 = t ? A2 : A3; int c1i = t ? A2i : A3i;
    float c2 = t ? B2 : B1; int c2i = t ? B2i : B1i;
    bool u = (c2 < c1) || (c2 == c1 && c2i < c1i);
    float r3 = u ? c2 : c1; int r3i = u ? c2i : c1i;
    v1 = A1; i1 = A1i; v2 = r2; i2 = r2i; v3 = r3; i3 = r3i;
}

// ---------------- init: zero wsq + loss ----------------
__global__ void init_kernel(float* __restrict__ wsq, double* __restrict__ lossAcc) {
    int i = blockIdx.x * 256 + threadIdx.x;
    if (i < F * K) wsq[i] = 0.f;
    if (i == 0) *lossAcc = 0.0;
}

// ---------------- x -> fp16 ----------------
__global__ void split_x(const float* __restrict__ x, ushort* __restrict__ xh) {
    int i = (blockIdx.x * 256 + threadIdx.x) * 4;
    float4 v = *(const float4*)(x + i);
    ushort4 h;
#pragma unroll
    for (int j = 0; j < 4; ++j) {
        _Float16 hv = (_Float16)(((const float*)&v)[j]);
        ((ushort*)&h)[j] = *(ushort*)&hv;
    }
    *(ushort4*)(xh + i) = h;
}

// ------- transpose w -> wt fp32 [f][k][d] + fp16 + fused ||w_k||^2 -------
__global__ void transpose_split_w(const float* __restrict__ w, float* __restrict__ wt,
                                  ushort* __restrict__ whT, float* __restrict__ wsq) {
    __shared__ float sd[32][33];
    int f  = blockIdx.z;
    int k0 = blockIdx.x * 32;
    int d0 = blockIdx.y * 32;
    const float* wf = w + (size_t)f * D * K;
    size_t obase = (size_t)f * K * D;
    int tx = threadIdx.x, ty = threadIdx.y;
#pragma unroll
    for (int i = 0; i < 4; ++i) {
        int d = ty + i * 8;
        sd[d][tx] = wf[(size_t)(d0 + d) * K + (k0 + tx)];
    }
    __syncthreads();
#pragma unroll
    for (int i = 0; i < 4; ++i) {
        int k = ty + i * 8;
        float v = sd[tx][k];
        size_t o = obase + (size_t)(k0 + k) * D + (d0 + tx);
        wt[o] = v;
        _Float16 hv = (_Float16)v;
        whT[o] = *(ushort*)&hv;
        float p = v * v;
#pragma unroll
        for (int off = 1; off < 32; off <<= 1) p += __shfl_xor(p, off);
        if (tx == 0) atomicAdd(&wsq[f * K + k0 + k], p);
    }
}

// ---------------- MFMA fp16 1-pass GEMM + top-3 ----------------
// A (64 rows, full D) resident in LDS seg-major; W double-buffered, 8 KB/stage.
// LDS ushort units: A [0,16384)  W0 [16384,20480)  W1 [20480,24576)  -> 48 KiB
__global__ __launch_bounds__(512, 4) void gemm_mfma_top3(
        const ushort* __restrict__ xh, const ushort* __restrict__ whT,
        const float* __restrict__ wsq, float4* __restrict__ top3v)
{
    __shared__ ushort lds[24576];   // 48 KiB
    const int bid  = blockIdx.x;
    const int f    = bid >> 6;             // 64 consecutive blocks share f (W L2-hot)
    const int m0   = (bid & 63) * 64;
    const int tid  = threadIdx.x;
    const int lane = tid & 63;
    const int wave = tid >> 6;             // 0..7
    const int mw   = wave >> 2;            // 0..1 : 32-row half
    const int nw   = wave & 3;             // 0..3 : 32-col quarter of the 128-chunk
    const int quad = lane >> 4, l15 = lane & 15;

    const ushort* xhb = xh  + ((size_t)f * B + m0) * D;
    const ushort* whb = whT + (size_t)f * K * D;

    // W staging indices (constant per thread): stage s covers chunk c=s>>3, d0=(s&7)*32
    const int wq_ = tid >> 7;              // d-seg 0..3 within the 32-d slab
    const int wn_ = tid & 127;             // col 0..127 within the chunk
    const ushort* wbase = whb + (size_t)wn_ * D + wq_ * 8;

    // ---- prologue: stage A seg-major [seg 0..31][row 0..63][8] + W stage 0
#pragma unroll
    for (int i = 0; i < 4; ++i) {
        int linear = i * 512 + tid;        // 0..2047 16B-slots
        int s = linear >> 6, row = linear & 63;
        async_load16(xhb + (size_t)row * D + s * 8, lds + linear * 8);
    }
    async_load16(wbase, lds + 16384 + tid * 8);

    float v1[8], v2[8];
    int   i1[8], i2[8];
#pragma unroll
    for (int s = 0; s < 8; ++s) {
        v1[s] = FLT_MAX; v2[s] = FLT_MAX; i1[s] = 0x7fffffff; i2[s] = 0x7fffffff;
    }

    f32x4 acc[2][2];
#pragma unroll
    for (int mt = 0; mt < 2; ++mt)
#pragma unroll
        for (int nt = 0; nt < 2; ++nt)
            acc[mt][nt] = (f32x4){0.f, 0.f, 0.f, 0.f};

    for (int s = 0; s < 64; ++s) {
        // barrier: stage-s W load complete everywhere; stage-(s-1) reads of the
        // other buffer done -> safe to overwrite it with stage s+1
        __syncthreads();
        if (s + 1 < 64) {
            int c  = (s + 1) >> 3;
            int d0 = ((s + 1) & 7) * 32;
            async_load16(wbase + (size_t)c * 128 * D + d0,
                         lds + 16384 + ((s + 1) & 1) * 4096 + tid * 8);
        }

        const int wb = 16384 + (s & 1) * 4096;
        const int sA = (s & 7) * 4 + quad;
        f16x8 ah[2];
#pragma unroll
        for (int mt = 0; mt < 2; ++mt)
            ah[mt] = *(const f16x8*)(lds + sA * 512 + (mw * 32 + mt * 16 + l15) * 8);
#pragma unroll
        for (int nt = 0; nt < 2; ++nt) {
            f16x8 bh = *(const f16x8*)(lds + wb + quad * 1024 + (nw * 32 + nt * 16 + l15) * 8);
#pragma unroll
            for (int mt = 0; mt < 2; ++mt)
                acc[mt][nt] = __builtin_amdgcn_mfma_f32_16x16x32_f16(ah[mt], bh, acc[mt][nt], 0, 0, 0);
        }

        if ((s & 7) == 7) {
            // epilogue: fold this 128-column chunk into per-lane top-2
            int n0 = (s >> 3) * 128;
#pragma unroll
            for (int nt = 0; nt < 2; ++nt) {
                int ng = n0 + nw * 32 + nt * 16 + l15;
                float wq = wsq[f * K + ng];
#pragma unroll
                for (int mt = 0; mt < 2; ++mt) {
#pragma unroll
                    for (int r = 0; r < 4; ++r) {
                        int sl = mt * 4 + r;
                        float sc = fmaf(-2.f, acc[mt][nt][r], wq);
                        if (sc < v1[sl]) { v2[sl] = v1[sl]; i2[sl] = i1[sl]; v1[sl] = sc; i1[sl] = ng; }
                        else if (sc < v2[sl]) { v2[sl] = sc; i2[sl] = ng; }
                    }
                }
                acc[0][nt] = (f32x4){0.f, 0.f, 0.f, 0.f};
                acc[1][nt] = (f32x4){0.f, 0.f, 0.f, 0.f};
            }
        }
    }

    // extend to top-3 and butterfly-merge among the 16 l15 lanes (fixed quad)
    float v3[8]; int i3[8];
#pragma unroll
    for (int s = 0; s < 8; ++s) { v3[s] = FLT_MAX; i3[s] = 0x7fffffff; }
#pragma unroll
    for (int s = 0; s < 8; ++s) {
#pragma unroll
        for (int off = 1; off < 16; off <<= 1) {
            float w1 = __shfl_xor(v1[s], off); int j1 = __shfl_xor(i1[s], off);
            float w2 = __shfl_xor(v2[s], off); int j2 = __shfl_xor(i2[s], off);
            float w3 = __shfl_xor(v3[s], off); int j3 = __shfl_xor(i3[s], off);
            merge3(v1[s], i1[s], v2[s], i2[s], v3[s], i3[s], w1, j1, w2, j2, w3, j3);
        }
    }

    // cross-wave (nw 0..3) merge via LDS: [64 rows][4 nw][2 float4]
    __syncthreads();                       // all compute/LDS reads done
    float4* mrg = (float4*)lds;
    if (l15 == 0) {
#pragma unroll
        for (int mt = 0; mt < 2; ++mt)
#pragma unroll
            for (int r = 0; r < 4; ++r) {
                int s = mt * 4 + r;
                int rl = mw * 32 + mt * 16 + quad * 4 + r;
                mrg[(rl * 4 + nw) * 2 + 0] = make_float4(v1[s], __int_as_float(i1[s]),
                                                         v2[s], __int_as_float(i2[s]));
                mrg[(rl * 4 + nw) * 2 + 1] = make_float4(v3[s], __int_as_float(i3[s]), 0.f, 0.f);
            }
    }
    __syncthreads();
    if (nw == 0 && l15 == 0) {
#pragma unroll
        for (int mt = 0; mt < 2; ++mt)
#pragma unroll
            for (int r = 0; r < 4; ++r) {
                int rl = mw * 32 + mt * 16 + quad * 4 + r;
                float4 ta = mrg[(rl * 4 + 0) * 2 + 0];
                float4 tb = mrg[(rl * 4 + 0) * 2 + 1];
                float bv1 = ta.x, bv2 = ta.z, bv3 = tb.x;
                int   bi1 = __float_as_int(ta.y), bi2 = __float_as_int(ta.w),
                      bi3 = __float_as_int(tb.y);
#pragma unroll
                for (int q = 1; q < 4; ++q) {
                    float4 oa = mrg[(rl * 4 + q) * 2 + 0];
                    float4 ob = mrg[(rl * 4 + q) * 2 + 1];
                    merge3(bv1, bi1, bv2, bi2, bv3, bi3,
                           oa.x, __float_as_int(oa.y), oa.z, __float_as_int(oa.w),
                           ob.x, __float_as_int(ob.y));
                }
                size_t orow = (size_t)f * B + m0 + rl;
                top3v[orow * 2 + 0] = make_float4(bv1, __int_as_float(bi1),
                                                  bv2, __int_as_float(bi2));
                top3v[orow * 2 + 1] = make_float4(bv3, __int_as_float(bi3), 0.f, 0.f);
            }
    }
}

// -------- fp64 refine + gather + loss; exact-check c2/c3 when gap < THR --------
__global__ __launch_bounds__(256) void refine_gather(
        const float* __restrict__ x, const float* __restrict__ wt,
        const float4* __restrict__ top3v, float* __restrict__ out,
        double* __restrict__ lossAcc) {
    __shared__ double lpart[4];
    int tid  = threadIdx.x;
    int wv   = tid >> 6;
    int lane = tid & 63;
    double lsum = 0.0;
    for (int it = 0; it < 16; ++it) {
        size_t row = ((size_t)blockIdx.x * 16 + it) * 4 + wv;
        int f = (int)(row >> 12);
        float4 ta = top3v[row * 2 + 0];
        float4 tb = top3v[row * 2 + 1];
        int c1 = __float_as_int(ta.y);
        const float* xr = x + row * D;
        float4 xv = ((const float4*)xr)[lane];

        const float* w1 = wt + ((size_t)f * K + c1) * D;
        float4 a  = ((const float4*)w1)[lane];
        double s1 = 0.0;
#pragma unroll
        for (int j = 0; j < 4; ++j) {
            double d1 = (double)((const float*)&xv)[j] - (double)((const float*)&a)[j];
            s1 = fma(d1, d1, s1);
        }
#pragma unroll
        for (int off = 1; off < 64; off <<= 1) s1 += __shfl_xor(s1, off);

        float4 q = a;
        double sel = s1;
        int selc = c1;

        if (ta.z - ta.x < THR) {   // candidate 2 ambiguous (wave-uniform)
            int c2 = __float_as_int(ta.w);
            const float* w2 = wt + ((size_t)f * K + c2) * D;
            float4 b = ((const float4*)w2)[lane];
            double s2 = 0.0;
#pragma unroll
            for (int j = 0; j < 4; ++j) {
                double d2 = (double)((const float*)&xv)[j] - (double)((const float*)&b)[j];
                s2 = fma(d2, d2, s2);
            }
#pragma unroll
            for (int off = 1; off < 64; off <<= 1) s2 += __shfl_xor(s2, off);
            if ((s2 < sel) || (s2 == sel && c2 < selc)) { q = b; sel = s2; selc = c2; }
        }
        if (tb.x - ta.x < THR) {   // candidate 3 ambiguous (wave-uniform)
            int c3 = __float_as_int(tb.y);
            const float* w3 = wt + ((size_t)f * K + c3) * D;
            float4 b = ((const float4*)w3)[lane];
            double s3 = 0.0;
#pragma unroll
            for (int j = 0; j < 4; ++j) {
                double d3 = (double)((const float*)&xv)[j] - (double)((const float*)&b)[j];
                s3 = fma(d3, d3, s3);
            }
#pragma unroll
            for (int off = 1; off < 64; off <<= 1) s3 += __shfl_xor(s3, off);
            if ((s3 < sel) || (s3 == sel && c3 < selc)) { q = b; sel = s3; selc = c3; }
        }
        ((float4*)(out + row * D))[lane] = q;
        if (lane == 0) lsum += sel;
    }
    if (lane == 0) lpart[wv] = lsum;
    __syncthreads();
    if (tid == 0) {
        double tsum = lpart[0] + lpart[1] + lpart[2] + lpart[3];
        atomicAdd(lossAcc, tsum);
    }
}

__global__ void finish_loss(const double* __restrict__ lossAcc,
                            float* __restrict__ out_loss) {
    if (threadIdx.x == 0)
        *out_loss = (float)(0.25 * (*lossAcc) / ((double)F * (double)B * (double)D));
}

extern "C" void kernel_launch(void* const* d_in, const int* in_sizes, int n_in,
                              void* d_out, int out_size, void* d_ws, size_t ws_size,
                              hipStream_t stream) {
    const float* x = (const float*)d_in[0];   // [F,B,D]
    const float* w = (const float*)d_in[1];   // [F,D,K]
    float* out = (float*)d_out;

    ushort* xh    = (ushort*)((char*)d_ws + XH_OFF);
    ushort* whT   = (ushort*)((char*)d_ws + WHT_OFF);
    float*  wt    = (float*)((char*)d_ws + WT_OFF);
    float*  wsq   = (float*)((char*)d_ws + WSQ_OFF);
    float4* top3v = (float4*)((char*)d_ws + TOP3_OFF);
    double* lossAcc = (double*)((char*)d_ws + LOSS_OFF);

    init_kernel<<<dim3(64), 256, 0, stream>>>(wsq, lossAcc);
    split_x<<<dim3(F * B * D / 1024), 256, 0, stream>>>(x, xh);
    transpose_split_w<<<dim3(K / 32, D / 32, F), dim3(32, 8), 0, stream>>>(w, wt, whT, wsq);
    gemm_mfma_top3<<<dim3((B / 64) * F), 512, 0, stream>>>(xh, whT, wsq, top3v);
    refine_gather<<<dim3(F * B / 64), 256, 0, stream>>>(x, wt, top3v, out, lossAcc);
    finish_loss<<<1, 64, 0, stream>>>(lossAcc, out + (size_t)F * B * D);
}

// Round 3
// 293.243 us; speedup vs baseline: 3.1414x; 1.0930x over previous
//
#include <hip/hip_runtime.h>
#include <cstdint>
#include <cfloat>

#define F 16
#define B 4096
#define D 256
#define K 1024

typedef __attribute__((ext_vector_type(8))) _Float16 f16x8;
typedef __attribute__((ext_vector_type(4))) float f32x4;

// ---- workspace layout (bytes) ----
#define WHT_OFF  0u            // F*K*D fp16 transposed [f][k][d] = 8388608
#define WT_OFF   8388608u      // F*K*D fp32 transposed = 16777216
#define WSQ_OFF  25165824u     // F*K fp32 = 65536
#define TOP3_OFF 25231360u     // F*B * 32B {v1,i1,v2,i2,v3,i3,_,_} = 2 MB
#define LOSS_OFF 27328512u

#define THR 0.012f             // refine ambiguity threshold (~13 sigma of fp16 GEMM err)

__device__ __forceinline__ void async_load16(const void* g, void* l) {
    __builtin_amdgcn_global_load_lds(
        (const __attribute__((address_space(1))) void*)g,
        (__attribute__((address_space(3))) void*)l, 16, 0, 0);
}

// merge two sorted top-3 lists (value asc, index tie-break asc) -> top-3
__device__ __forceinline__ void merge3(
        float& v1, int& i1, float& v2, int& i2, float& v3, int& i3,
        float w1, int j1, float w2, int j2, float w3, int j3)
{
    bool s = (w1 < v1) || (w1 == v1 && j1 < i1);
    float A1 = s ? w1 : v1; int A1i = s ? j1 : i1;
    float A2 = s ? w2 : v2; int A2i = s ? j2 : i2;
    float A3 = s ? w3 : v3; int A3i = s ? j3 : i3;
    float B1 = s ? v1 : w1; int B1i = s ? i1 : j1;
    float B2 = s ? v2 : w2; int B2i = s ? i2 : j2;
    bool t = (B1 < A2) || (B1 == A2 && B1i < A2i);
    float r2 = t ? B1 : A2; int r2i = t ? B1i : A2i;
    float c1 = t ? A2 : A3; int c1i = t ? A2i : A3i;
    float c2 = t ? B2 : B1; int c2i = t ? B2i : B1i;
    bool u = (c2 < c1) || (c2 == c1 && c2i < c1i);
    float r3 = u ? c2 : c1; int r3i = u ? c2i : c1i;
    v1 = A1; i1 = A1i; v2 = r2; i2 = r2i; v3 = r3; i3 = r3i;
}

// ------- transpose w -> wt fp32 [f][k][d] + fp16 + ||w_k||^2 (no atomics) -------
// grid (K/32, F), block (32,8). Each block owns 32 k-columns over ALL of D.
__global__ void transpose_w(const float* __restrict__ w, float* __restrict__ wt,
                            ushort* __restrict__ whT, float* __restrict__ wsq,
                            double* __restrict__ lossAcc) {
    __shared__ float sd[32][33];
    int f  = blockIdx.y;
    int k0 = blockIdx.x * 32;
    int tx = threadIdx.x, ty = threadIdx.y;
    if (f == 0 && blockIdx.x == 0 && tx == 0 && ty == 0) *lossAcc = 0.0;
    const float* wf = w + (size_t)f * D * K;
    size_t obase = (size_t)f * K * D;
    float ksum[4] = {0.f, 0.f, 0.f, 0.f};
    for (int d0 = 0; d0 < D; d0 += 32) {
        __syncthreads();   // previous tile's reads of sd done
#pragma unroll
        for (int i = 0; i < 4; ++i) {
            int d = ty + i * 8;
            sd[d][tx] = wf[(size_t)(d0 + d) * K + (k0 + tx)];
        }
        __syncthreads();
#pragma unroll
        for (int i = 0; i < 4; ++i) {
            int k = ty + i * 8;
            float v = sd[tx][k];
            size_t o = obase + (size_t)(k0 + k) * D + (d0 + tx);
            wt[o] = v;
            _Float16 hv = (_Float16)v;
            whT[o] = *(ushort*)&hv;
            float p = v * v;
#pragma unroll
            for (int off = 1; off < 32; off <<= 1) p += __shfl_xor(p, off);
            if (tx == 0) ksum[i] += p;
        }
    }
    if (tx == 0) {
#pragma unroll
        for (int i = 0; i < 4; ++i)
            wsq[f * K + k0 + ty + i * 8] = ksum[i];
    }
}

// ---------------- MFMA fp16 GEMM + top-3, counted-vmcnt pipeline ----------------
// LDS (ushort units): A [0,16384) seg-major | W 4 bufs [16384,32768) | wsq [32768,34816)
// Per stage: wait vmcnt(2) -> s_barrier -> issue prefetch s+3 -> 4 ds_read_b128 -> 4 MFMA.
// No other VMEM in the loop, so the per-wave vmcnt counting is exact.
__global__ __launch_bounds__(512, 4) void gemm_mfma_top3(
        const float* __restrict__ x, const ushort* __restrict__ whT,
        const float* __restrict__ wsq, float4* __restrict__ top3v)
{
    __shared__ __align__(16) ushort lds[34816];   // 68 KiB -> 2 blocks/CU
    const int bid  = blockIdx.x;
    const int f    = bid >> 6;             // 64 consecutive blocks share f (W L2-hot)
    const int m0   = (bid & 63) * 64;
    const int tid  = threadIdx.x;
    const int lane = tid & 63;
    const int wave = tid >> 6;             // 0..7
    const int mw   = wave >> 2;            // 0..1 : 32-row half
    const int nw   = wave & 3;             // 0..3 : 32-col quarter of the 128-chunk
    const int quad = lane >> 4, l15 = lane & 15;

    const ushort* whb = whT + (size_t)f * K * D;
    const int wq_ = tid >> 7;              // d-seg 0..3 within a 32-d slab
    const int wn_ = tid & 127;             // col 0..127 within the chunk
    const ushort* wbase = whb + (size_t)wn_ * D + wq_ * 8;

    // ---- prologue: convert A fp32->fp16 into LDS seg-major [seg][row][8]
    const float* xb = x + ((size_t)f * B + m0) * D;
#pragma unroll
    for (int i = 0; i < 8; ++i) {
        int v = tid * 8 + i;               // float4 index: row = v>>6, pos = v&63
        int row = v >> 6, fp = v & 63;
        float4 xv = *(const float4*)(xb + (size_t)row * D + fp * 4);
        ushort4 h;
        _Float16 h0 = (_Float16)xv.x; ((ushort*)&h)[0] = *(ushort*)&h0;
        _Float16 h1 = (_Float16)xv.y; ((ushort*)&h)[1] = *(ushort*)&h1;
        _Float16 h2 = (_Float16)xv.z; ((ushort*)&h)[2] = *(ushort*)&h2;
        _Float16 h3 = (_Float16)xv.w; ((ushort*)&h)[3] = *(ushort*)&h3;
        *(ushort4*)(&lds[(fp >> 1) * 512 + row * 8 + (fp & 1) * 4]) = h;
    }
    // wsq slab -> LDS (DMA; waves 0..3 only — per-wave vmcnt stays consistent)
    if (tid < 256) async_load16(wsq + f * K + tid * 4, &lds[32768 + tid * 8]);
    // W prefetch stages 0,1,2
#pragma unroll
    for (int p = 0; p < 3; ++p)
        async_load16(wbase + p * 32, &lds[16384 + p * 4096 + tid * 8]);

    asm volatile("s_waitcnt lgkmcnt(0)" ::: "memory");   // own A ds_writes done
    __builtin_amdgcn_s_barrier();                        // all waves' A visible
    asm volatile("" ::: "memory");

    float v1[8], v2[8];
    int   i1[8], i2[8];
#pragma unroll
    for (int s = 0; s < 8; ++s) {
        v1[s] = FLT_MAX; v2[s] = FLT_MAX; i1[s] = 0x7fffffff; i2[s] = 0x7fffffff;
    }

    const float* wsql = (const float*)(&lds[32768]);

    for (int c = 0; c < 8; ++c) {
        f32x4 acc[2][2];
#pragma unroll
        for (int mt = 0; mt < 2; ++mt)
#pragma unroll
            for (int nt = 0; nt < 2; ++nt)
                acc[mt][nt] = (f32x4){0.f, 0.f, 0.f, 0.f};

#pragma unroll
        for (int dd = 0; dd < 8; ++dd) {
            const int s = c * 8 + dd;
            // stage-s load (3 stages old) complete; 2 newer stay in flight
            asm volatile("s_waitcnt vmcnt(2)" ::: "memory");
            __builtin_amdgcn_s_barrier();
            asm volatile("" ::: "memory");
            // prefetch stage s+3 into the buffer freed at this barrier
            int sp = s + 3; if (sp > 63) sp = 63;   // tail: harmless dummy reloads
            async_load16(wbase + (size_t)(sp >> 3) * (128 * D) + (sp & 7) * 32,
                         &lds[16384 + ((s + 3) & 3) * 4096 + tid * 8]);

            const ushort* wlds = &lds[16384 + (s & 3) * 4096];
            const int sA = dd * 4 + quad;
            f16x8 a0 = *(const f16x8*)(&lds[sA * 512 + (mw * 32 + l15) * 8]);
            f16x8 a1 = *(const f16x8*)(&lds[sA * 512 + (mw * 32 + 16 + l15) * 8]);
            f16x8 b0 = *(const f16x8*)(&wlds[quad * 1024 + (nw * 32 + l15) * 8]);
            f16x8 b1 = *(const f16x8*)(&wlds[quad * 1024 + (nw * 32 + 16 + l15) * 8]);
            acc[0][0] = __builtin_amdgcn_mfma_f32_16x16x32_f16(a0, b0, acc[0][0], 0, 0, 0);
            acc[1][0] = __builtin_amdgcn_mfma_f32_16x16x32_f16(a1, b0, acc[1][0], 0, 0, 0);
            acc[0][1] = __builtin_amdgcn_mfma_f32_16x16x32_f16(a0, b1, acc[0][1], 0, 0, 0);
            acc[1][1] = __builtin_amdgcn_mfma_f32_16x16x32_f16(a1, b1, acc[1][1], 0, 0, 0);
        }

        // epilogue: fold this 128-column chunk into per-lane top-2 (wsq from LDS)
#pragma unroll
        for (int nt = 0; nt < 2; ++nt) {
            int ng = c * 128 + nw * 32 + nt * 16 + l15;
            float wq = wsql[ng];
#pragma unroll
            for (int mt = 0; mt < 2; ++mt) {
#pragma unroll
                for (int r = 0; r < 4; ++r) {
                    int sl = mt * 4 + r;
                    float sc = fmaf(-2.f, acc[mt][nt][r], wq);
                    if (sc < v1[sl]) { v2[sl] = v1[sl]; i2[sl] = i1[sl]; v1[sl] = sc; i1[sl] = ng; }
                    else if (sc < v2[sl]) { v2[sl] = sc; i2[sl] = ng; }
                }
            }
        }
    }

    // extend to top-3 and butterfly-merge among the 16 l15 lanes (fixed quad)
    float v3[8]; int i3[8];
#pragma unroll
    for (int s = 0; s < 8; ++s) { v3[s] = FLT_MAX; i3[s] = 0x7fffffff; }
#pragma unroll
    for (int s = 0; s < 8; ++s) {
#pragma unroll
        for (int off = 1; off < 16; off <<= 1) {
            float w1 = __shfl_xor(v1[s], off); int j1 = __shfl_xor(i1[s], off);
            float w2 = __shfl_xor(v2[s], off); int j2 = __shfl_xor(i2[s], off);
            float w3 = __shfl_xor(v3[s], off); int j3 = __shfl_xor(i3[s], off);
            merge3(v1[s], i1[s], v2[s], i2[s], v3[s], i3[s], w1, j1, w2, j2, w3, j3);
        }
    }

    // cross-wave (nw 0..3) merge via LDS: [64 rows][4 nw][2 float4]
    __syncthreads();                       // drains everything (incl. tail dummies)
    float4* mrg = (float4*)lds;
    if (l15 == 0) {
#pragma unroll
        for (int mt = 0; mt < 2; ++mt)
#pragma unroll
            for (int r = 0; r < 4; ++r) {
                int s = mt * 4 + r;
                int rl = mw * 32 + mt * 16 + quad * 4 + r;
                mrg[(rl * 4 + nw) * 2 + 0] = make_float4(v1[s], __int_as_float(i1[s]),
                                                         v2[s], __int_as_float(i2[s]));
                mrg[(rl * 4 + nw) * 2 + 1] = make_float4(v3[s], __int_as_float(i3[s]), 0.f, 0.f);
            }
    }
    __syncthreads();
    if (nw == 0 && l15 == 0) {
#pragma unroll
        for (int mt = 0; mt < 2; ++mt)
#pragma unroll
            for (int r = 0; r < 4; ++r) {
                int rl = mw * 32 + mt * 16 + quad * 4 + r;
                float4 ta = mrg[(rl * 4 + 0) * 2 + 0];
                float4 tb = mrg[(rl * 4 + 0) * 2 + 1];
                float bv1 = ta.x, bv2 = ta.z, bv3 = tb.x;
                int   bi1 = __float_as_int(ta.y), bi2 = __float_as_int(ta.w),
                      bi3 = __float_as_int(tb.y);
#pragma unroll
                for (int q = 1; q < 4; ++q) {
                    float4 oa = mrg[(rl * 4 + q) * 2 + 0];
                    float4 ob = mrg[(rl * 4 + q) * 2 + 1];
                    merge3(bv1, bi1, bv2, bi2, bv3, bi3,
                           oa.x, __float_as_int(oa.y), oa.z, __float_as_int(oa.w),
                           ob.x, __float_as_int(ob.y));
                }
                size_t orow = (size_t)f * B + m0 + rl;
                top3v[orow * 2 + 0] = make_float4(bv1, __int_as_float(bi1),
                                                  bv2, __int_as_float(bi2));
                top3v[orow * 2 + 1] = make_float4(bv3, __int_as_float(bi3), 0.f, 0.f);
            }
    }
}

// -------- fp64 refine + gather + loss; exact-check c2/c3 when gap < THR --------
__global__ __launch_bounds__(256) void refine_gather(
        const float* __restrict__ x, const float* __restrict__ wt,
        const float4* __restrict__ top3v, float* __restrict__ out,
        double* __restrict__ lossAcc) {
    __shared__ double lpart[4];
    int tid  = threadIdx.x;
    int wv   = tid >> 6;
    int lane = tid & 63;
    double lsum = 0.0;
    for (int it = 0; it < 16; ++it) {
        size_t row = ((size_t)blockIdx.x * 16 + it) * 4 + wv;
        int f = (int)(row >> 12);
        float4 ta = top3v[row * 2 + 0];
        float4 tb = top3v[row * 2 + 1];
        int c1 = __float_as_int(ta.y);
        const float* xr = x + row * D;
        float4 xv = ((const float4*)xr)[lane];

        const float* w1 = wt + ((size_t)f * K + c1) * D;
        float4 a  = ((const float4*)w1)[lane];
        double s1 = 0.0;
#pragma unroll
        for (int j = 0; j < 4; ++j) {
            double d1 = (double)((const float*)&xv)[j] - (double)((const float*)&a)[j];
            s1 = fma(d1, d1, s1);
        }
#pragma unroll
        for (int off = 1; off < 64; off <<= 1) s1 += __shfl_xor(s1, off);

        float4 q = a;
        double sel = s1;
        int selc = c1;

        if (ta.z - ta.x < THR) {   // candidate 2 ambiguous (wave-uniform)
            int c2 = __float_as_int(ta.w);
            const float* w2 = wt + ((size_t)f * K + c2) * D;
            float4 b = ((const float4*)w2)[lane];
            double s2 = 0.0;
#pragma unroll
            for (int j = 0; j < 4; ++j) {
                double d2 = (double)((const float*)&xv)[j] - (double)((const float*)&b)[j];
                s2 = fma(d2, d2, s2);
            }
#pragma unroll
            for (int off = 1; off < 64; off <<= 1) s2 += __shfl_xor(s2, off);
            if ((s2 < sel) || (s2 == sel && c2 < selc)) { q = b; sel = s2; selc = c2; }
        }
        if (tb.x - ta.x < THR) {   // candidate 3 ambiguous (wave-uniform)
            int c3 = __float_as_int(tb.y);
            const float* w3 = wt + ((size_t)f * K + c3) * D;
            float4 b = ((const float4*)w3)[lane];
            double s3 = 0.0;
#pragma unroll
            for (int j = 0; j < 4; ++j) {
                double d3 = (double)((const float*)&xv)[j] - (double)((const float*)&b)[j];
                s3 = fma(d3, d3, s3);
            }
#pragma unroll
            for (int off = 1; off < 64; off <<= 1) s3 += __shfl_xor(s3, off);
            if ((s3 < sel) || (s3 == sel && c3 < selc)) { q = b; sel = s3; selc = c3; }
        }
        ((float4*)(out + row * D))[lane] = q;
        if (lane == 0) lsum += sel;
    }
    if (lane == 0) lpart[wv] = lsum;
    __syncthreads();
    if (tid == 0) {
        double tsum = lpart[0] + lpart[1] + lpart[2] + lpart[3];
        atomicAdd(lossAcc, tsum);
    }
}

__global__ void finish_loss(const double* __restrict__ lossAcc,
                            float* __restrict__ out_loss) {
    if (threadIdx.x == 0)
        *out_loss = (float)(0.25 * (*lossAcc) / ((double)F * (double)B * (double)D));
}

extern "C" void kernel_launch(void* const* d_in, const int* in_sizes, int n_in,
                              void* d_out, int out_size, void* d_ws, size_t ws_size,
                              hipStream_t stream) {
    const float* x = (const float*)d_in[0];   // [F,B,D]
    const float* w = (const float*)d_in[1];   // [F,D,K]
    float* out = (float*)d_out;

    ushort* whT   = (ushort*)((char*)d_ws + WHT_OFF);
    float*  wt    = (float*)((char*)d_ws + WT_OFF);
    float*  wsq   = (float*)((char*)d_ws + WSQ_OFF);
    float4* top3v = (float4*)((char*)d_ws + TOP3_OFF);
    double* lossAcc = (double*)((char*)d_ws + LOSS_OFF);

    transpose_w<<<dim3(K / 32, F), dim3(32, 8), 0, stream>>>(w, wt, whT, wsq, lossAcc);
    gemm_mfma_top3<<<dim3((B / 64) * F), 512, 0, stream>>>(x, whT, wsq, top3v);
    refine_gather<<<dim3(F * B / 64), 256, 0, stream>>>(x, wt, top3v, out, lossAcc);
    finish_loss<<<1, 64, 0, stream>>>(lossAcc, out + (size_t)F * B * D);
}

// Round 4
// 279.427 us; speedup vs baseline: 3.2967x; 1.0494x over previous
//
#include <hip/hip_runtime.h>
#include <cstdint>
#include <cfloat>

#define F 16
#define B 4096
#define D 256
#define K 1024

typedef __attribute__((ext_vector_type(8))) _Float16 f16x8;
typedef __attribute__((ext_vector_type(4))) float f32x4;

// ---- workspace layout (bytes) ----
#define WHT_OFF  0u            // F*K*D fp16 transposed [f][k][d] = 8388608
#define WT_OFF   8388608u      // F*K*D fp32 transposed = 16777216
#define WSQ_OFF  25165824u     // F*K fp32 = 65536
#define TOP3_OFF 25231360u     // F*B * 32B {v1,i1,v2,i2,v3,i3,_,_} = 2 MB
#define LOSS_OFF 27328512u

#define THR 0.012f             // refine ambiguity threshold (~13 sigma of fp16 GEMM err)

__device__ __forceinline__ void async_load16(const void* g, void* l) {
    __builtin_amdgcn_global_load_lds(
        (const __attribute__((address_space(1))) void*)g,
        (__attribute__((address_space(3))) void*)l, 16, 0, 0);
}

// merge two sorted top-3 lists (value asc, index tie-break asc) -> top-3
__device__ __forceinline__ void merge3(
        float& v1, int& i1, float& v2, int& i2, float& v3, int& i3,
        float w1, int j1, float w2, int j2, float w3, int j3)
{
    bool s = (w1 < v1) || (w1 == v1 && j1 < i1);
    float A1 = s ? w1 : v1; int A1i = s ? j1 : i1;
    float A2 = s ? w2 : v2; int A2i = s ? j2 : i2;
    float A3 = s ? w3 : v3; int A3i = s ? j3 : i3;
    float B1 = s ? v1 : w1; int B1i = s ? i1 : j1;
    float B2 = s ? v2 : w2; int B2i = s ? i2 : j2;
    bool t = (B1 < A2) || (B1 == A2 && B1i < A2i);
    float r2 = t ? B1 : A2; int r2i = t ? B1i : A2i;
    float c1 = t ? A2 : A3; int c1i = t ? A2i : A3i;
    float c2 = t ? B2 : B1; int c2i = t ? B2i : B1i;
    bool u = (c2 < c1) || (c2 == c1 && c2i < c1i);
    float r3 = u ? c2 : c1; int r3i = u ? c2i : c1i;
    v1 = A1; i1 = A1i; v2 = r2; i2 = r2i; v3 = r3; i3 = r3i;
}

// ------- transpose w -> wt fp32 [f][k][d] + fp16 + ||w_k||^2 (no atomics) -------
__global__ void transpose_w(const float* __restrict__ w, float* __restrict__ wt,
                            ushort* __restrict__ whT, float* __restrict__ wsq,
                            double* __restrict__ lossAcc) {
    __shared__ float sd[32][33];
    int f  = blockIdx.y;
    int k0 = blockIdx.x * 32;
    int tx = threadIdx.x, ty = threadIdx.y;
    if (f == 0 && blockIdx.x == 0 && tx == 0 && ty == 0) *lossAcc = 0.0;
    const float* wf = w + (size_t)f * D * K;
    size_t obase = (size_t)f * K * D;
    float ksum[4] = {0.f, 0.f, 0.f, 0.f};
    for (int d0 = 0; d0 < D; d0 += 32) {
        __syncthreads();
#pragma unroll
        for (int i = 0; i < 4; ++i) {
            int d = ty + i * 8;
            sd[d][tx] = wf[(size_t)(d0 + d) * K + (k0 + tx)];
        }
        __syncthreads();
#pragma unroll
        for (int i = 0; i < 4; ++i) {
            int k = ty + i * 8;
            float v = sd[tx][k];
            size_t o = obase + (size_t)(k0 + k) * D + (d0 + tx);
            wt[o] = v;
            _Float16 hv = (_Float16)v;
            whT[o] = *(ushort*)&hv;
            float p = v * v;
#pragma unroll
            for (int off = 1; off < 32; off <<= 1) p += __shfl_xor(p, off);
            if (tx == 0) ksum[i] += p;
        }
    }
    if (tx == 0) {
#pragma unroll
        for (int i = 0; i < 4; ++i)
            wsq[f * K + k0 + ty + i * 8] = ksum[i];
    }
}

// ---------------- MFMA fp16 GEMM + top-3, A in registers ----------------
// A (per wave: 32 rows x K=256) held in 16 f16x8 regs. W staged 16 KB/stage
// (128 cols x 64 d), 4 LDS buffers, prefetch depth 2, counted vmcnt(2).
// LDS (ushort units): W 4x8192 [0,32768) | wsq [32768,34816)  -> 68 KiB
__global__ __launch_bounds__(512, 4) void gemm_mfma_top3(
        const float* __restrict__ x, const ushort* __restrict__ whT,
        const float* __restrict__ wsq, float4* __restrict__ top3v)
{
    __shared__ __align__(16) ushort lds[34816];
    const int bid  = blockIdx.x;
    const int f    = bid >> 6;             // 64 consecutive blocks share f (W L2-hot)
    const int m0   = (bid & 63) * 64;
    const int tid  = threadIdx.x;
    const int lane = tid & 63;
    const int wave = tid >> 6;             // 0..7
    const int mw   = wave >> 2;            // 0..1 : 32-row half
    const int nw   = wave & 3;             // 0..3 : 32-col quarter of the 128-chunk
    const int quad = lane >> 4, l15 = lane & 15;

    const ushort* whb = whT + (size_t)f * K * D;
    const int col_ = tid & 127;            // staging col within chunk
    const int sg_  = tid >> 7;             // staging d-seg 0..3
    const ushort* wsrc = whb + (size_t)col_ * D + sg_ * 8;

    // ---- A into registers: a[mt][ks] = rows mw*32+mt*16+l15, d = ks*32+quad*8
    const float* xb = x + ((size_t)f * B + m0) * D;
    f16x8 a[2][8];
#pragma unroll
    for (int mt = 0; mt < 2; ++mt) {
#pragma unroll
        for (int ks = 0; ks < 8; ++ks) {
            const float* src = xb + (size_t)(mw * 32 + mt * 16 + l15) * D + ks * 32 + quad * 8;
            float4 u0 = *(const float4*)src;
            float4 u1 = *(const float4*)(src + 4);
            f16x8 h;
            h[0] = (_Float16)u0.x; h[1] = (_Float16)u0.y;
            h[2] = (_Float16)u0.z; h[3] = (_Float16)u0.w;
            h[4] = (_Float16)u1.x; h[5] = (_Float16)u1.y;
            h[6] = (_Float16)u1.z; h[7] = (_Float16)u1.w;
            a[mt][ks] = h;
        }
    }

    // wsq slab -> LDS (waves 0..3; drained before loop)
    if (tid < 256) async_load16(wsq + f * K + tid * 4, &lds[32768 + tid * 8]);
    // W prefetch stages 0,1 (chunk 0, slabs 0,1)
#pragma unroll
    for (int p = 0; p < 2; ++p) {
        async_load16(wsrc + p * 64,      &lds[p * 8192 + tid * 8]);
        async_load16(wsrc + p * 64 + 32, &lds[p * 8192 + 4096 + tid * 8]);
    }
    asm volatile("s_waitcnt vmcnt(0)" ::: "memory");
    __builtin_amdgcn_s_barrier();

    float v1[8], v2[8];
    unsigned int ii[8];                    // i1 | (i2<<16)
#pragma unroll
    for (int s = 0; s < 8; ++s) { v1[s] = FLT_MAX; v2[s] = FLT_MAX; ii[s] = 0xFFFFFFFFu; }

    const float* wsql = (const float*)(&lds[32768]);

#pragma unroll 1
    for (int c = 0; c < 8; ++c) {
        f32x4 acc[2][2];
#pragma unroll
        for (int mt = 0; mt < 2; ++mt)
#pragma unroll
            for (int nt = 0; nt < 2; ++nt)
                acc[mt][nt] = (f32x4){0.f, 0.f, 0.f, 0.f};

#pragma unroll
        for (int sl = 0; sl < 4; ++sl) {
            // stage s = c*4+sl: its loads (issued 2 stages ago) complete; 1 newer stays
            asm volatile("s_waitcnt vmcnt(2)" ::: "memory");
            __builtin_amdgcn_s_barrier();
            // prefetch stage s+2 into buffer freed at this barrier
            int sp = c * 4 + sl + 2; if (sp > 31) sp = 31;   // tail: harmless dummy
            const ushort* gsrc = wsrc + (size_t)(sp >> 2) * (128 * D) + (sp & 3) * 64;
            const int db = ((sl + 2) & 3) * 8192;
            async_load16(gsrc,      &lds[db + tid * 8]);
            async_load16(gsrc + 32, &lds[db + 4096 + tid * 8]);

            const ushort* wb = &lds[sl * 8192];
#pragma unroll
            for (int kk = 0; kk < 2; ++kk) {
                f16x8 b0 = *(const f16x8*)(&wb[(kk * 4 + quad) * 1024 + (nw * 32 + l15) * 8]);
                f16x8 b1 = *(const f16x8*)(&wb[(kk * 4 + quad) * 1024 + (nw * 32 + 16 + l15) * 8]);
                const int ks = sl * 2 + kk;
                acc[0][0] = __builtin_amdgcn_mfma_f32_16x16x32_f16(a[0][ks], b0, acc[0][0], 0, 0, 0);
                acc[1][0] = __builtin_amdgcn_mfma_f32_16x16x32_f16(a[1][ks], b0, acc[1][0], 0, 0, 0);
                acc[0][1] = __builtin_amdgcn_mfma_f32_16x16x32_f16(a[0][ks], b1, acc[0][1], 0, 0, 0);
                acc[1][1] = __builtin_amdgcn_mfma_f32_16x16x32_f16(a[1][ks], b1, acc[1][1], 0, 0, 0);
            }
        }

        // epilogue: fold this 128-col chunk into per-lane top-2 (packed indices)
#pragma unroll
        for (int nt = 0; nt < 2; ++nt) {
            int ng = c * 128 + nw * 32 + nt * 16 + l15;
            float wq = wsql[ng];
#pragma unroll
            for (int mt = 0; mt < 2; ++mt) {
#pragma unroll
                for (int r = 0; r < 4; ++r) {
                    int sl = mt * 4 + r;
                    float sc = fmaf(-2.f, acc[mt][nt][r], wq);
                    bool lt1 = sc < v1[sl];
                    bool lt2 = sc < v2[sl];
                    unsigned int lo = ii[sl] & 0xFFFFu;
                    unsigned int cpush = (lo << 16) | (unsigned int)ng;
                    unsigned int crep  = lo | ((unsigned int)ng << 16);
                    ii[sl] = lt1 ? cpush : (lt2 ? crep : ii[sl]);
                    v2[sl] = lt1 ? v1[sl] : (lt2 ? sc : v2[sl]);
                    v1[sl] = lt1 ? sc : v1[sl];
                }
            }
        }
    }

    asm volatile("s_waitcnt vmcnt(0)" ::: "memory");   // drain tail dummy DMAs
    __syncthreads();

    // unpack, extend to top-3, butterfly-merge among the 16 l15 lanes
    float v3[8]; int i1[8], i2[8], i3[8];
#pragma unroll
    for (int s = 0; s < 8; ++s) {
        i1[s] = (int)(ii[s] & 0xFFFFu);
        i2[s] = (int)(ii[s] >> 16);
        v3[s] = FLT_MAX; i3[s] = 0x7fffffff;
    }
#pragma unroll
    for (int s = 0; s < 8; ++s) {
#pragma unroll
        for (int off = 1; off < 16; off <<= 1) {
            float w1 = __shfl_xor(v1[s], off); int j1 = __shfl_xor(i1[s], off);
            float w2 = __shfl_xor(v2[s], off); int j2 = __shfl_xor(i2[s], off);
            float w3 = __shfl_xor(v3[s], off); int j3 = __shfl_xor(i3[s], off);
            merge3(v1[s], i1[s], v2[s], i2[s], v3[s], i3[s], w1, j1, w2, j2, w3, j3);
        }
    }

    // cross-wave (nw 0..3) merge via LDS: [64 rows][4 nw][2 float4]
    float4* mrg = (float4*)lds;
    if (l15 == 0) {
#pragma unroll
        for (int mt = 0; mt < 2; ++mt)
#pragma unroll
            for (int r = 0; r < 4; ++r) {
                int s = mt * 4 + r;
                int rl = mw * 32 + mt * 16 + quad * 4 + r;
                mrg[(rl * 4 + nw) * 2 + 0] = make_float4(v1[s], __int_as_float(i1[s]),
                                                         v2[s], __int_as_float(i2[s]));
                mrg[(rl * 4 + nw) * 2 + 1] = make_float4(v3[s], __int_as_float(i3[s]), 0.f, 0.f);
            }
    }
    __syncthreads();
    if (nw == 0 && l15 == 0) {
#pragma unroll
        for (int mt = 0; mt < 2; ++mt)
#pragma unroll
            for (int r = 0; r < 4; ++r) {
                int rl = mw * 32 + mt * 16 + quad * 4 + r;
                float4 ta = mrg[(rl * 4 + 0) * 2 + 0];
                float4 tb = mrg[(rl * 4 + 0) * 2 + 1];
                float bv1 = ta.x, bv2 = ta.z, bv3 = tb.x;
                int   bi1 = __float_as_int(ta.y), bi2 = __float_as_int(ta.w),
                      bi3 = __float_as_int(tb.y);
#pragma unroll
                for (int q = 1; q < 4; ++q) {
                    float4 oa = mrg[(rl * 4 + q) * 2 + 0];
                    float4 ob = mrg[(rl * 4 + q) * 2 + 1];
                    merge3(bv1, bi1, bv2, bi2, bv3, bi3,
                           oa.x, __float_as_int(oa.y), oa.z, __float_as_int(oa.w),
                           ob.x, __float_as_int(ob.y));
                }
                size_t orow = (size_t)f * B + m0 + rl;
                top3v[orow * 2 + 0] = make_float4(bv1, __int_as_float(bi1),
                                                  bv2, __int_as_float(bi2));
                top3v[orow * 2 + 1] = make_float4(bv3, __int_as_float(bi3), 0.f, 0.f);
            }
    }
}

// -------- fp64 refine + gather + loss; exact-check c2/c3 when gap < THR --------
__global__ __launch_bounds__(256) void refine_gather(
        const float* __restrict__ x, const float* __restrict__ wt,
        const float4* __restrict__ top3v, float* __restrict__ out,
        double* __restrict__ lossAcc) {
    __shared__ double lpart[4];
    int tid  = threadIdx.x;
    int wv   = tid >> 6;
    int lane = tid & 63;
    double lsum = 0.0;
    for (int it = 0; it < 16; ++it) {
        size_t row = ((size_t)blockIdx.x * 16 + it) * 4 + wv;
        int f = (int)(row >> 12);
        float4 ta = top3v[row * 2 + 0];
        float4 tb = top3v[row * 2 + 1];
        int c1 = __float_as_int(ta.y);
        const float* xr = x + row * D;
        float4 xv = ((const float4*)xr)[lane];

        const float* w1 = wt + ((size_t)f * K + c1) * D;
        float4 a  = ((const float4*)w1)[lane];
        double s1 = 0.0;
#pragma unroll
        for (int j = 0; j < 4; ++j) {
            double d1 = (double)((const float*)&xv)[j] - (double)((const float*)&a)[j];
            s1 = fma(d1, d1, s1);
        }
#pragma unroll
        for (int off = 1; off < 64; off <<= 1) s1 += __shfl_xor(s1, off);

        float4 q = a;
        double sel = s1;
        int selc = c1;

        if (ta.z - ta.x < THR) {   // candidate 2 ambiguous (wave-uniform)
            int c2 = __float_as_int(ta.w);
            const float* w2 = wt + ((size_t)f * K + c2) * D;
            float4 b = ((const float4*)w2)[lane];
            double s2 = 0.0;
#pragma unroll
            for (int j = 0; j < 4; ++j) {
                double d2 = (double)((const float*)&xv)[j] - (double)((const float*)&b)[j];
                s2 = fma(d2, d2, s2);
            }
#pragma unroll
            for (int off = 1; off < 64; off <<= 1) s2 += __shfl_xor(s2, off);
            if ((s2 < sel) || (s2 == sel && c2 < selc)) { q = b; sel = s2; selc = c2; }
        }
        if (tb.x - ta.x < THR) {   // candidate 3 ambiguous (wave-uniform)
            int c3 = __float_as_int(tb.y);
            const float* w3 = wt + ((size_t)f * K + c3) * D;
            float4 b = ((const float4*)w3)[lane];
            double s3 = 0.0;
#pragma unroll
            for (int j = 0; j < 4; ++j) {
                double d3 = (double)((const float*)&xv)[j] - (double)((const float*)&b)[j];
                s3 = fma(d3, d3, s3);
            }
#pragma unroll
            for (int off = 1; off < 64; off <<= 1) s3 += __shfl_xor(s3, off);
            if ((s3 < sel) || (s3 == sel && c3 < selc)) { q = b; sel = s3; selc = c3; }
        }
        ((float4*)(out + row * D))[lane] = q;
        if (lane == 0) lsum += sel;
    }
    if (lane == 0) lpart[wv] = lsum;
    __syncthreads();
    if (tid == 0) {
        double tsum = lpart[0] + lpart[1] + lpart[2] + lpart[3];
        atomicAdd(lossAcc, tsum);
    }
}

__global__ void finish_loss(const double* __restrict__ lossAcc,
                            float* __restrict__ out_loss) {
    if (threadIdx.x == 0)
        *out_loss = (float)(0.25 * (*lossAcc) / ((double)F * (double)B * (double)D));
}

extern "C" void kernel_launch(void* const* d_in, const int* in_sizes, int n_in,
                              void* d_out, int out_size, void* d_ws, size_t ws_size,
                              hipStream_t stream) {
    const float* x = (const float*)d_in[0];   // [F,B,D]
    const float* w = (const float*)d_in[1];   // [F,D,K]
    float* out = (float*)d_out;

    ushort* whT   = (ushort*)((char*)d_ws + WHT_OFF);
    float*  wt    = (float*)((char*)d_ws + WT_OFF);
    float*  wsq   = (float*)((char*)d_ws + WSQ_OFF);
    float4* top3v = (float4*)((char*)d_ws + TOP3_OFF);
    double* lossAcc = (double*)((char*)d_ws + LOSS_OFF);

    transpose_w<<<dim3(K / 32, F), dim3(32, 8), 0, stream>>>(w, wt, whT, wsq, lossAcc);
    gemm_mfma_top3<<<dim3((B / 64) * F), 512, 0, stream>>>(x, whT, wsq, top3v);
    refine_gather<<<dim3(F * B / 64), 256, 0, stream>>>(x, wt, top3v, out, lossAcc);
    finish_loss<<<1, 64, 0, stream>>>(lossAcc, out + (size_t)F * B * D);
}

// Round 5
// 279.059 us; speedup vs baseline: 3.3011x; 1.0013x over previous
//
#include <hip/hip_runtime.h>
#include <cstdint>
#include <cfloat>

#define F 16
#define B 4096
#define D 256
#define K 1024

typedef __attribute__((ext_vector_type(8))) _Float16 f16x8;
typedef __attribute__((ext_vector_type(4))) float f32x4;

// ---- workspace layout (bytes) ----
#define WHT_OFF  0u            // F*K*D fp16 transposed [f][k][d] = 8388608
#define WT_OFF   8388608u      // F*K*D fp32 transposed = 16777216
#define WSQ_OFF  25165824u     // F*K fp32 = 65536
#define TOP3_OFF 25231360u     // F*B * 32B {v1,i1,v2,i2,v3,i3,_,_} = 2 MB
#define LOSS_OFF 27328512u

#define THR 0.012f             // refine ambiguity threshold (~13 sigma of fp16 GEMM err)

__device__ __forceinline__ void async_load16(const void* g, void* l) {
    __builtin_amdgcn_global_load_lds(
        (const __attribute__((address_space(1))) void*)g,
        (__attribute__((address_space(3))) void*)l, 16, 0, 0);
}

// merge two sorted top-3 lists (value asc, index tie-break asc) -> top-3
__device__ __forceinline__ void merge3(
        float& v1, int& i1, float& v2, int& i2, float& v3, int& i3,
        float w1, int j1, float w2, int j2, float w3, int j3)
{
    bool s = (w1 < v1) || (w1 == v1 && j1 < i1);
    float A1 = s ? w1 : v1; int A1i = s ? j1 : i1;
    float A2 = s ? w2 : v2; int A2i = s ? j2 : i2;
    float A3 = s ? w3 : v3; int A3i = s ? j3 : i3;
    float B1 = s ? v1 : w1; int B1i = s ? i1 : j1;
    float B2 = s ? v2 : w2; int B2i = s ? i2 : j2;
    bool t = (B1 < A2) || (B1 == A2 && B1i < A2i);
    float r2 = t ? B1 : A2; int r2i = t ? B1i : A2i;
    float c1 = t ? A2 : A3; int c1i = t ? A2i : A3i;
    float c2 = t ? B2 : B1; int c2i = t ? B2i : B1i;
    bool u = (c2 < c1) || (c2 == c1 && c2i < c1i);
    float r3 = u ? c2 : c1; int r3i = u ? c2i : c1i;
    v1 = A1; i1 = A1i; v2 = r2; i2 = r2i; v3 = r3; i3 = r3i;
}

// ------- transpose w -> wt fp32 [f][k][d] + fp16 + ||w_k||^2 (no atomics) -------
__global__ void transpose_w(const float* __restrict__ w, float* __restrict__ wt,
                            ushort* __restrict__ whT, float* __restrict__ wsq,
                            double* __restrict__ lossAcc) {
    __shared__ float sd[32][33];
    int f  = blockIdx.y;
    int k0 = blockIdx.x * 32;
    int tx = threadIdx.x, ty = threadIdx.y;
    if (f == 0 && blockIdx.x == 0 && tx == 0 && ty == 0) *lossAcc = 0.0;
    const float* wf = w + (size_t)f * D * K;
    size_t obase = (size_t)f * K * D;
    float ksum[4] = {0.f, 0.f, 0.f, 0.f};
    for (int d0 = 0; d0 < D; d0 += 32) {
        __syncthreads();
#pragma unroll
        for (int i = 0; i < 4; ++i) {
            int d = ty + i * 8;
            sd[d][tx] = wf[(size_t)(d0 + d) * K + (k0 + tx)];
        }
        __syncthreads();
#pragma unroll
        for (int i = 0; i < 4; ++i) {
            int k = ty + i * 8;
            float v = sd[tx][k];
            size_t o = obase + (size_t)(k0 + k) * D + (d0 + tx);
            wt[o] = v;
            _Float16 hv = (_Float16)v;
            whT[o] = *(ushort*)&hv;
            float p = v * v;
#pragma unroll
            for (int off = 1; off < 32; off <<= 1) p += __shfl_xor(p, off);
            if (tx == 0) ksum[i] += p;
        }
    }
    if (tx == 0) {
#pragma unroll
        for (int i = 0; i < 4; ++i)
            wsq[f * K + k0 + ty + i * 8] = ksum[i];
    }
}

// ---------------- MFMA fp16 GEMM + top-3, A in registers ----------------
// A (per wave: 32 rows x K=256) held in 16 f16x8 regs (64 VGPR). W staged
// 16 KB/stage (128 cols x 64 d), 4 LDS buffers, prefetch depth 2, vmcnt(2).
// LDS (ushort units): W 4x8192 [0,32768) | wsq [32768,34816)  -> 68 KiB.
// waves_per_eu(4): VGPR cap 128 (needs ~120). NOTE: __launch_bounds__ 2nd arg
// behaves as min-BLOCKS/CU here (R1/R4 evidence: (512,4)->64 VGPR, (512,6)->40)
// -> do NOT use it; amdgpu_waves_per_eu is the precise control.
__global__ __launch_bounds__(512) __attribute__((amdgpu_waves_per_eu(4)))
void gemm_mfma_top3(
        const float* __restrict__ x, const ushort* __restrict__ whT,
        const float* __restrict__ wsq, float4* __restrict__ top3v)
{
    __shared__ __align__(16) ushort lds[34816];
    const int bid  = blockIdx.x;
    const int f    = bid >> 6;             // 64 consecutive blocks share f (W L2-hot)
    const int m0   = (bid & 63) * 64;
    const int tid  = threadIdx.x;
    const int lane = tid & 63;
    const int wave = tid >> 6;             // 0..7
    const int mw   = wave >> 2;            // 0..1 : 32-row half
    const int nw   = wave & 3;             // 0..3 : 32-col quarter of the 128-chunk
    const int quad = lane >> 4, l15 = lane & 15;

    const ushort* whb = whT + (size_t)f * K * D;
    const int col_ = tid & 127;            // staging col within chunk
    const int sg_  = tid >> 7;             // staging d-seg 0..3
    const ushort* wsrc = whb + (size_t)col_ * D + sg_ * 8;

    // ---- A into registers: a[mt][ks] = rows mw*32+mt*16+l15, d = ks*32+quad*8
    const float* xb = x + ((size_t)f * B + m0) * D;
    f16x8 a[2][8];
#pragma unroll
    for (int mt = 0; mt < 2; ++mt) {
#pragma unroll
        for (int ks = 0; ks < 8; ++ks) {
            const float* src = xb + (size_t)(mw * 32 + mt * 16 + l15) * D + ks * 32 + quad * 8;
            float4 u0 = *(const float4*)src;
            float4 u1 = *(const float4*)(src + 4);
            f16x8 h;
            h[0] = (_Float16)u0.x; h[1] = (_Float16)u0.y;
            h[2] = (_Float16)u0.z; h[3] = (_Float16)u0.w;
            h[4] = (_Float16)u1.x; h[5] = (_Float16)u1.y;
            h[6] = (_Float16)u1.z; h[7] = (_Float16)u1.w;
            a[mt][ks] = h;
        }
    }

    // wsq slab -> LDS (waves 0..3; drained before loop)
    if (tid < 256) async_load16(wsq + f * K + tid * 4, &lds[32768 + tid * 8]);
    // W prefetch stages 0,1 (chunk 0, slabs 0,1)
#pragma unroll
    for (int p = 0; p < 2; ++p) {
        async_load16(wsrc + p * 64,      &lds[p * 8192 + tid * 8]);
        async_load16(wsrc + p * 64 + 32, &lds[p * 8192 + 4096 + tid * 8]);
    }
    asm volatile("s_waitcnt vmcnt(0)" ::: "memory");
    __builtin_amdgcn_s_barrier();

    float v1[8], v2[8];
    unsigned int ii[8];                    // i1 | (i2<<16)
#pragma unroll
    for (int s = 0; s < 8; ++s) { v1[s] = FLT_MAX; v2[s] = FLT_MAX; ii[s] = 0xFFFFFFFFu; }

    const float* wsql = (const float*)(&lds[32768]);

#pragma unroll 1
    for (int c = 0; c < 8; ++c) {
        f32x4 acc[2][2];
#pragma unroll
        for (int mt = 0; mt < 2; ++mt)
#pragma unroll
            for (int nt = 0; nt < 2; ++nt)
                acc[mt][nt] = (f32x4){0.f, 0.f, 0.f, 0.f};

#pragma unroll
        for (int sl = 0; sl < 4; ++sl) {
            // stage s = c*4+sl: its loads (issued 2 stages ago) complete; newest 2 stay
            asm volatile("s_waitcnt vmcnt(2)" ::: "memory");
            __builtin_amdgcn_s_barrier();
            // prefetch stage s+2 into buffer freed at this barrier
            int sp = c * 4 + sl + 2; if (sp > 31) sp = 31;   // tail: harmless dummy
            const ushort* gsrc = wsrc + (size_t)(sp >> 2) * (128 * D) + (sp & 3) * 64;
            const int db = ((sl + 2) & 3) * 8192;
            async_load16(gsrc,      &lds[db + tid * 8]);
            async_load16(gsrc + 32, &lds[db + 4096 + tid * 8]);

            const ushort* wb = &lds[sl * 8192];
#pragma unroll
            for (int kk = 0; kk < 2; ++kk) {
                f16x8 b0 = *(const f16x8*)(&wb[(kk * 4 + quad) * 1024 + (nw * 32 + l15) * 8]);
                f16x8 b1 = *(const f16x8*)(&wb[(kk * 4 + quad) * 1024 + (nw * 32 + 16 + l15) * 8]);
                const int ks = sl * 2 + kk;
                acc[0][0] = __builtin_amdgcn_mfma_f32_16x16x32_f16(a[0][ks], b0, acc[0][0], 0, 0, 0);
                acc[1][0] = __builtin_amdgcn_mfma_f32_16x16x32_f16(a[1][ks], b0, acc[1][0], 0, 0, 0);
                acc[0][1] = __builtin_amdgcn_mfma_f32_16x16x32_f16(a[0][ks], b1, acc[0][1], 0, 0, 0);
                acc[1][1] = __builtin_amdgcn_mfma_f32_16x16x32_f16(a[1][ks], b1, acc[1][1], 0, 0, 0);
            }
        }

        // epilogue: fold this 128-col chunk into per-lane top-2 (packed indices)
#pragma unroll
        for (int nt = 0; nt < 2; ++nt) {
            int ng = c * 128 + nw * 32 + nt * 16 + l15;
            float wq = wsql[ng];
#pragma unroll
            for (int mt = 0; mt < 2; ++mt) {
#pragma unroll
                for (int r = 0; r < 4; ++r) {
                    int sl = mt * 4 + r;
                    float sc = fmaf(-2.f, acc[mt][nt][r], wq);
                    bool lt1 = sc < v1[sl];
                    bool lt2 = sc < v2[sl];
                    unsigned int lo = ii[sl] & 0xFFFFu;
                    unsigned int cpush = (lo << 16) | (unsigned int)ng;
                    unsigned int crep  = lo | ((unsigned int)ng << 16);
                    ii[sl] = lt1 ? cpush : (lt2 ? crep : ii[sl]);
                    v2[sl] = lt1 ? v1[sl] : (lt2 ? sc : v2[sl]);
                    v1[sl] = lt1 ? sc : v1[sl];
                }
            }
        }
    }

    asm volatile("s_waitcnt vmcnt(0)" ::: "memory");   // drain tail dummy DMAs
    __syncthreads();

    // unpack, extend to top-3, butterfly-merge among the 16 l15 lanes
    float v3[8]; int i1[8], i2[8], i3[8];
#pragma unroll
    for (int s = 0; s < 8; ++s) {
        i1[s] = (int)(ii[s] & 0xFFFFu);
        i2[s] = (int)(ii[s] >> 16);
        v3[s] = FLT_MAX; i3[s] = 0x7fffffff;
    }
#pragma unroll
    for (int s = 0; s < 8; ++s) {
#pragma unroll
        for (int off = 1; off < 16; off <<= 1) {
            float w1 = __shfl_xor(v1[s], off); int j1 = __shfl_xor(i1[s], off);
            float w2 = __shfl_xor(v2[s], off); int j2 = __shfl_xor(i2[s], off);
            float w3 = __shfl_xor(v3[s], off); int j3 = __shfl_xor(i3[s], off);
            merge3(v1[s], i1[s], v2[s], i2[s], v3[s], i3[s], w1, j1, w2, j2, w3, j3);
        }
    }

    // cross-wave (nw 0..3) merge via LDS: [64 rows][4 nw][2 float4]
    float4* mrg = (float4*)lds;
    if (l15 == 0) {
#pragma unroll
        for (int mt = 0; mt < 2; ++mt)
#pragma unroll
            for (int r = 0; r < 4; ++r) {
                int s = mt * 4 + r;
                int rl = mw * 32 + mt * 16 + quad * 4 + r;
                mrg[(rl * 4 + nw) * 2 + 0] = make_float4(v1[s], __int_as_float(i1[s]),
                                                         v2[s], __int_as_float(i2[s]));
                mrg[(rl * 4 + nw) * 2 + 1] = make_float4(v3[s], __int_as_float(i3[s]), 0.f, 0.f);
            }
    }
    __syncthreads();
    if (nw == 0 && l15 == 0) {
#pragma unroll
        for (int mt = 0; mt < 2; ++mt)
#pragma unroll
            for (int r = 0; r < 4; ++r) {
                int rl = mw * 32 + mt * 16 + quad * 4 + r;
                float4 ta = mrg[(rl * 4 + 0) * 2 + 0];
                float4 tb = mrg[(rl * 4 + 0) * 2 + 1];
                float bv1 = ta.x, bv2 = ta.z, bv3 = tb.x;
                int   bi1 = __float_as_int(ta.y), bi2 = __float_as_int(ta.w),
                      bi3 = __float_as_int(tb.y);
#pragma unroll
                for (int q = 1; q < 4; ++q) {
                    float4 oa = mrg[(rl * 4 + q) * 2 + 0];
                    float4 ob = mrg[(rl * 4 + q) * 2 + 1];
                    merge3(bv1, bi1, bv2, bi2, bv3, bi3,
                           oa.x, __float_as_int(oa.y), oa.z, __float_as_int(oa.w),
                           ob.x, __float_as_int(ob.y));
                }
                size_t orow = (size_t)f * B + m0 + rl;
                top3v[orow * 2 + 0] = make_float4(bv1, __int_as_float(bi1),
                                                  bv2, __int_as_float(bi2));
                top3v[orow * 2 + 1] = make_float4(bv3, __int_as_float(bi3), 0.f, 0.f);
            }
    }
}

// -------- fp64 refine + gather + loss; exact-check c2/c3 when gap < THR --------
__global__ __launch_bounds__(256) void refine_gather(
        const float* __restrict__ x, const float* __restrict__ wt,
        const float4* __restrict__ top3v, float* __restrict__ out,
        double* __restrict__ lossAcc) {
    __shared__ double lpart[4];
    int tid  = threadIdx.x;
    int wv   = tid >> 6;
    int lane = tid & 63;
    double lsum = 0.0;
    for (int it = 0; it < 16; ++it) {
        size_t row = ((size_t)blockIdx.x * 16 + it) * 4 + wv;
        int f = (int)(row >> 12);
        float4 ta = top3v[row * 2 + 0];
        float4 tb = top3v[row * 2 + 1];
        int c1 = __float_as_int(ta.y);
        const float* xr = x + row * D;
        float4 xv = ((const float4*)xr)[lane];

        const float* w1 = wt + ((size_t)f * K + c1) * D;
        float4 a  = ((const float4*)w1)[lane];
        double s1 = 0.0;
#pragma unroll
        for (int j = 0; j < 4; ++j) {
            double d1 = (double)((const float*)&xv)[j] - (double)((const float*)&a)[j];
            s1 = fma(d1, d1, s1);
        }
#pragma unroll
        for (int off = 1; off < 64; off <<= 1) s1 += __shfl_xor(s1, off);

        float4 q = a;
        double sel = s1;
        int selc = c1;

        if (ta.z - ta.x < THR) {   // candidate 2 ambiguous (wave-uniform)
            int c2 = __float_as_int(ta.w);
            const float* w2 = wt + ((size_t)f * K + c2) * D;
            float4 b = ((const float4*)w2)[lane];
            double s2 = 0.0;
#pragma unroll
            for (int j = 0; j < 4; ++j) {
                double d2 = (double)((const float*)&xv)[j] - (double)((const float*)&b)[j];
                s2 = fma(d2, d2, s2);
            }
#pragma unroll
            for (int off = 1; off < 64; off <<= 1) s2 += __shfl_xor(s2, off);
            if ((s2 < sel) || (s2 == sel && c2 < selc)) { q = b; sel = s2; selc = c2; }
        }
        if (tb.x - ta.x < THR) {   // candidate 3 ambiguous (wave-uniform)
            int c3 = __float_as_int(tb.y);
            const float* w3 = wt + ((size_t)f * K + c3) * D;
            float4 b = ((const float4*)w3)[lane];
            double s3 = 0.0;
#pragma unroll
            for (int j = 0; j < 4; ++j) {
                double d3 = (double)((const float*)&xv)[j] - (double)((const float*)&b)[j];
                s3 = fma(d3, d3, s3);
            }
#pragma unroll
            for (int off = 1; off < 64; off <<= 1) s3 += __shfl_xor(s3, off);
            if ((s3 < sel) || (s3 == sel && c3 < selc)) { q = b; sel = s3; selc = c3; }
        }
        ((float4*)(out + row * D))[lane] = q;
        if (lane == 0) lsum += sel;
    }
    if (lane == 0) lpart[wv] = lsum;
    __syncthreads();
    if (tid == 0) {
        double tsum = lpart[0] + lpart[1] + lpart[2] + lpart[3];
        atomicAdd(lossAcc, tsum);
    }
}

__global__ void finish_loss(const double* __restrict__ lossAcc,
                            float* __restrict__ out_loss) {
    if (threadIdx.x == 0)
        *out_loss = (float)(0.25 * (*lossAcc) / ((double)F * (double)B * (double)D));
}

extern "C" void kernel_launch(void* const* d_in, const int* in_sizes, int n_in,
                              void* d_out, int out_size, void* d_ws, size_t ws_size,
                              hipStream_t stream) {
    const float* x = (const float*)d_in[0];   // [F,B,D]
    const float* w = (const float*)d_in[1];   // [F,D,K]
    float* out = (float*)d_out;

    ushort* whT   = (ushort*)((char*)d_ws + WHT_OFF);
    float*  wt    = (float*)((char*)d_ws + WT_OFF);
    float*  wsq   = (float*)((char*)d_ws + WSQ_OFF);
    float4* top3v = (float4*)((char*)d_ws + TOP3_OFF);
    double* lossAcc = (double*)((char*)d_ws + LOSS_OFF);

    transpose_w<<<dim3(K / 32, F), dim3(32, 8), 0, stream>>>(w, wt, whT, wsq, lossAcc);
    gemm_mfma_top3<<<dim3((B / 64) * F), 512, 0, stream>>>(x, whT, wsq, top3v);
    refine_gather<<<dim3(F * B / 64), 256, 0, stream>>>(x, wt, top3v, out, lossAcc);
    finish_loss<<<1, 64, 0, stream>>>(lossAcc, out + (size_t)F * B * D);
}

// Round 6
// 246.410 us; speedup vs baseline: 3.7385x; 1.1325x over previous
//
#include <hip/hip_runtime.h>
#include <cstdint>
#include <cfloat>

#define F 16
#define B 4096
#define D 256
#define K 1024

typedef __attribute__((ext_vector_type(8))) _Float16 f16x8;
typedef __attribute__((ext_vector_type(4))) float f32x4;

// ---- workspace layout (bytes) ----
#define WHT_OFF  0u            // F*K*D fp16 transposed [f][k][d] = 8388608
#define WT_OFF   8388608u      // F*K*D fp32 transposed = 16777216
#define WSQ_OFF  25165824u     // F*K fp32 = 65536
#define TOP3_OFF 25231360u     // F*B * 32B {v1,i1,v2,i2,v3,i3,_,_} = 2 MB
#define LOSS_OFF 27328512u

#define THR 0.012f             // refine ambiguity threshold (~13 sigma of fp16 GEMM err)

__device__ __forceinline__ void async_load16(const void* g, void* l) {
    __builtin_amdgcn_global_load_lds(
        (const __attribute__((address_space(1))) void*)g,
        (__attribute__((address_space(3))) void*)l, 16, 0, 0);
}

// merge two sorted top-3 lists (value asc, index tie-break asc) -> top-3
__device__ __forceinline__ void merge3(
        float& v1, int& i1, float& v2, int& i2, float& v3, int& i3,
        float w1, int j1, float w2, int j2, float w3, int j3)
{
    bool s = (w1 < v1) || (w1 == v1 && j1 < i1);
    float A1 = s ? w1 : v1; int A1i = s ? j1 : i1;
    float A2 = s ? w2 : v2; int A2i = s ? j2 : i2;
    float A3 = s ? w3 : v3; int A3i = s ? j3 : i3;
    float B1 = s ? v1 : w1; int B1i = s ? i1 : j1;
    float B2 = s ? v2 : w2; int B2i = s ? i2 : j2;
    bool t = (B1 < A2) || (B1 == A2 && B1i < A2i);
    float r2 = t ? B1 : A2; int r2i = t ? B1i : A2i;
    float c1 = t ? A2 : A3; int c1i = t ? A2i : A3i;
    float c2 = t ? B2 : B1; int c2i = t ? B2i : B1i;
    bool u = (c2 < c1) || (c2 == c1 && c2i < c1i);
    float r3 = u ? c2 : c1; int r3i = u ? c2i : c1i;
    v1 = A1; i1 = A1i; v2 = r2; i2 = r2i; v3 = r3; i3 = r3i;
}

// ------- transpose w -> wt fp32 [f][k][d] + fp16 + ||w_k||^2 (no atomics) -------
__global__ void transpose_w(const float* __restrict__ w, float* __restrict__ wt,
                            ushort* __restrict__ whT, float* __restrict__ wsq,
                            double* __restrict__ lossAcc) {
    __shared__ float sd[32][33];
    int f  = blockIdx.y;
    int k0 = blockIdx.x * 32;
    int tx = threadIdx.x, ty = threadIdx.y;
    if (f == 0 && blockIdx.x == 0 && tx == 0 && ty == 0) *lossAcc = 0.0;
    const float* wf = w + (size_t)f * D * K;
    size_t obase = (size_t)f * K * D;
    float ksum[4] = {0.f, 0.f, 0.f, 0.f};
    for (int d0 = 0; d0 < D; d0 += 32) {
        __syncthreads();
#pragma unroll
        for (int i = 0; i < 4; ++i) {
            int d = ty + i * 8;
            sd[d][tx] = wf[(size_t)(d0 + d) * K + (k0 + tx)];
        }
        __syncthreads();
#pragma unroll
        for (int i = 0; i < 4; ++i) {
            int k = ty + i * 8;
            float v = sd[tx][k];
            size_t o = obase + (size_t)(k0 + k) * D + (d0 + tx);
            wt[o] = v;
            _Float16 hv = (_Float16)v;
            whT[o] = *(ushort*)&hv;
            float p = v * v;
#pragma unroll
            for (int off = 1; off < 32; off <<= 1) p += __shfl_xor(p, off);
            if (tx == 0) ksum[i] += p;
        }
    }
    if (tx == 0) {
#pragma unroll
        for (int i = 0; i < 4; ++i)
            wsq[f * K + k0 + ty + i * 8] = ksum[i];
    }
}

// ---------------- MFMA fp16 GEMM + top-3, A in registers ----------------
// Wave grid 4 row-groups x 2 col-groups: per wave 16 rows x 64 cols.
// A (16 rows x K=256 per wave) in 8 f16x8 regs (32 VGPR). Top-2 state: 4 slots.
// Register budget model (R1-R5 evidence): budget = 512/waves_per_eu TOTAL
// (arch VGPR + AGPR unified on gfx950); at 4 waves/EU -> 128. This layout
// needs ~100 -> no spill (R4/R5's 32x32 layout needed ~147 -> 19-dword spill).
// W staged 16 KB/stage (128 cols x 64 d), 4 LDS buffers, depth 3, vmcnt(4).
// LDS (ushort units): W 4x8192 [0,32768) | wsq [32768,34816)  -> 68 KiB.
__global__ __launch_bounds__(512) __attribute__((amdgpu_waves_per_eu(4)))
void gemm_mfma_top3(
        const float* __restrict__ x, const ushort* __restrict__ whT,
        const float* __restrict__ wsq, float4* __restrict__ top3v)
{
    __shared__ __align__(16) ushort lds[34816];
    const int bid  = blockIdx.x;
    const int f    = bid >> 6;             // 64 consecutive blocks share f (W L2-hot)
    const int m0   = (bid & 63) * 64;
    const int tid  = threadIdx.x;
    const int lane = tid & 63;
    const int wave = tid >> 6;             // 0..7
    const int rw   = wave >> 1;            // 0..3 : 16-row group
    const int cw   = wave & 1;             // 0..1 : 64-col half of the 128-chunk
    const int quad = lane >> 4, l15 = lane & 15;

    const ushort* whb = whT + (size_t)f * K * D;
    const int col_ = tid & 127;            // staging col within chunk
    const int sg_  = tid >> 7;             // staging d-octet 0..3
    const ushort* wsrc = whb + (size_t)col_ * D + sg_ * 8;

    // ---- DMAs first: wsq slab + W stages 0,1,2 (depth 3)
    if (tid < 256) async_load16(wsq + f * K + tid * 4, &lds[32768 + tid * 8]);
#pragma unroll
    for (int p = 0; p < 3; ++p) {
        async_load16(wsrc + p * 64,      &lds[p * 8192 + tid * 8]);
        async_load16(wsrc + p * 64 + 32, &lds[p * 8192 + 4096 + tid * 8]);
    }

    // ---- A into registers: a[ks] = row rw*16+l15, d = ks*32 + quad*8 .. +8
    const float* xb = x + ((size_t)f * B + m0) * D;
    f16x8 a[8];
#pragma unroll
    for (int ks = 0; ks < 8; ++ks) {
        const float* src = xb + (size_t)(rw * 16 + l15) * D + ks * 32 + quad * 8;
        float4 u0 = *(const float4*)src;
        float4 u1 = *(const float4*)(src + 4);
        f16x8 h;
        h[0] = (_Float16)u0.x; h[1] = (_Float16)u0.y;
        h[2] = (_Float16)u0.z; h[3] = (_Float16)u0.w;
        h[4] = (_Float16)u1.x; h[5] = (_Float16)u1.y;
        h[6] = (_Float16)u1.z; h[7] = (_Float16)u1.w;
        a[ks] = h;
    }

    asm volatile("s_waitcnt vmcnt(0)" ::: "memory");   // A + prologue DMAs done
    __builtin_amdgcn_s_barrier();

    float v1[4], v2[4];
    unsigned int ii[4];                    // i1 | (i2<<16)
#pragma unroll
    for (int s = 0; s < 4; ++s) { v1[s] = FLT_MAX; v2[s] = FLT_MAX; ii[s] = 0xFFFFFFFFu; }

    const float* wsql = (const float*)(&lds[32768]);

#pragma unroll 1
    for (int c = 0; c < 8; ++c) {
        f32x4 acc[4];
#pragma unroll
        for (int nt = 0; nt < 4; ++nt) acc[nt] = (f32x4){0.f, 0.f, 0.f, 0.f};

#pragma unroll
        for (int sl = 0; sl < 4; ++sl) {
            const int s = c * 4 + sl;
            // stage-s loads (issued 3 stages ago) complete; 2 newer pairs stay
            asm volatile("s_waitcnt vmcnt(4)" ::: "memory");
            __builtin_amdgcn_s_barrier();
            // prefetch stage s+3 into buffer freed at this barrier ((sl-1)&3)
            int sp = s + 3; if (sp > 31) sp = 31;   // tail: harmless dummy reloads
            const ushort* gsrc = wsrc + (size_t)(sp >> 2) * (128 * D) + (sp & 3) * 64;
            const int db = ((sl + 3) & 3) * 8192;
            async_load16(gsrc,      &lds[db + tid * 8]);
            async_load16(gsrc + 32, &lds[db + 4096 + tid * 8]);

            const ushort* wb = &lds[sl * 8192];
#pragma unroll
            for (int kk = 0; kk < 2; ++kk) {
                const int ks = sl * 2 + kk;
                const int kb = (kk * 4 + quad) * 1024;
                f16x8 b0 = *(const f16x8*)(&wb[kb + (cw * 64 +  0 + l15) * 8]);
                f16x8 b1 = *(const f16x8*)(&wb[kb + (cw * 64 + 16 + l15) * 8]);
                f16x8 b2 = *(const f16x8*)(&wb[kb + (cw * 64 + 32 + l15) * 8]);
                f16x8 b3 = *(const f16x8*)(&wb[kb + (cw * 64 + 48 + l15) * 8]);
                acc[0] = __builtin_amdgcn_mfma_f32_16x16x32_f16(a[ks], b0, acc[0], 0, 0, 0);
                acc[1] = __builtin_amdgcn_mfma_f32_16x16x32_f16(a[ks], b1, acc[1], 0, 0, 0);
                acc[2] = __builtin_amdgcn_mfma_f32_16x16x32_f16(a[ks], b2, acc[2], 0, 0, 0);
                acc[3] = __builtin_amdgcn_mfma_f32_16x16x32_f16(a[ks], b3, acc[3], 0, 0, 0);
            }
        }

        // epilogue: fold this 128-col chunk into per-lane top-2 (4 row-slots)
#pragma unroll
        for (int nt = 0; nt < 4; ++nt) {
            int ng = c * 128 + cw * 64 + nt * 16 + l15;
            float wq = wsql[ng];
#pragma unroll
            for (int r = 0; r < 4; ++r) {
                float sc = fmaf(-2.f, acc[nt][r], wq);
                bool lt1 = sc < v1[r];
                bool lt2 = sc < v2[r];
                unsigned int lo = ii[r] & 0xFFFFu;
                unsigned int cpush = (lo << 16) | (unsigned int)ng;
                unsigned int crep  = lo | ((unsigned int)ng << 16);
                ii[r] = lt1 ? cpush : (lt2 ? crep : ii[r]);
                v2[r] = lt1 ? v1[r] : (lt2 ? sc : v2[r]);
                v1[r] = lt1 ? sc : v1[r];
            }
        }
    }

    asm volatile("s_waitcnt vmcnt(0)" ::: "memory");   // drain tail dummy DMAs
    __syncthreads();

    // unpack, extend to top-3, butterfly-merge among the 16 l15 lanes
    float v3[4]; int i1[4], i2[4], i3[4];
#pragma unroll
    for (int s = 0; s < 4; ++s) {
        i1[s] = (int)(ii[s] & 0xFFFFu);
        i2[s] = (int)(ii[s] >> 16);
        v3[s] = FLT_MAX; i3[s] = 0x7fffffff;
    }
#pragma unroll
    for (int s = 0; s < 4; ++s) {
#pragma unroll
        for (int off = 1; off < 16; off <<= 1) {
            float w1 = __shfl_xor(v1[s], off); int j1 = __shfl_xor(i1[s], off);
            float w2 = __shfl_xor(v2[s], off); int j2 = __shfl_xor(i2[s], off);
            float w3 = __shfl_xor(v3[s], off); int j3 = __shfl_xor(i3[s], off);
            merge3(v1[s], i1[s], v2[s], i2[s], v3[s], i3[s], w1, j1, w2, j2, w3, j3);
        }
    }

    // cross-wave (cw 0..1) merge via LDS: [64 rows][2 cw][2 float4]
    float4* mrg = (float4*)lds;
    if (l15 == 0) {
#pragma unroll
        for (int r = 0; r < 4; ++r) {
            int rl = rw * 16 + quad * 4 + r;
            mrg[(rl * 2 + cw) * 2 + 0] = make_float4(v1[r], __int_as_float(i1[r]),
                                                     v2[r], __int_as_float(i2[r]));
            mrg[(rl * 2 + cw) * 2 + 1] = make_float4(v3[r], __int_as_float(i3[r]), 0.f, 0.f);
        }
    }
    __syncthreads();
    if (cw == 0 && l15 == 0) {
#pragma unroll
        for (int r = 0; r < 4; ++r) {
            int rl = rw * 16 + quad * 4 + r;
            float4 ta = mrg[(rl * 2 + 0) * 2 + 0];
            float4 tb = mrg[(rl * 2 + 0) * 2 + 1];
            float bv1 = ta.x, bv2 = ta.z, bv3 = tb.x;
            int   bi1 = __float_as_int(ta.y), bi2 = __float_as_int(ta.w),
                  bi3 = __float_as_int(tb.y);
            float4 oa = mrg[(rl * 2 + 1) * 2 + 0];
            float4 ob = mrg[(rl * 2 + 1) * 2 + 1];
            merge3(bv1, bi1, bv2, bi2, bv3, bi3,
                   oa.x, __float_as_int(oa.y), oa.z, __float_as_int(oa.w),
                   ob.x, __float_as_int(ob.y));
            size_t orow = (size_t)f * B + m0 + rl;
            top3v[orow * 2 + 0] = make_float4(bv1, __int_as_float(bi1),
                                              bv2, __int_as_float(bi2));
            top3v[orow * 2 + 1] = make_float4(bv3, __int_as_float(bi3), 0.f, 0.f);
        }
    }
}

// -------- fp64 refine + gather + loss; exact-check c2/c3 when gap < THR --------
__global__ __launch_bounds__(256) void refine_gather(
        const float* __restrict__ x, const float* __restrict__ wt,
        const float4* __restrict__ top3v, float* __restrict__ out,
        double* __restrict__ lossAcc) {
    __shared__ double lpart[4];
    int tid  = threadIdx.x;
    int wv   = tid >> 6;
    int lane = tid & 63;
    double lsum = 0.0;
    for (int it = 0; it < 16; ++it) {
        size_t row = ((size_t)blockIdx.x * 16 + it) * 4 + wv;
        int f = (int)(row >> 12);
        float4 ta = top3v[row * 2 + 0];
        float4 tb = top3v[row * 2 + 1];
        int c1 = __float_as_int(ta.y);
        const float* xr = x + row * D;
        float4 xv = ((const float4*)xr)[lane];

        const float* w1 = wt + ((size_t)f * K + c1) * D;
        float4 a  = ((const float4*)w1)[lane];
        double s1 = 0.0;
#pragma unroll
        for (int j = 0; j < 4; ++j) {
            double d1 = (double)((const float*)&xv)[j] - (double)((const float*)&a)[j];
            s1 = fma(d1, d1, s1);
        }
#pragma unroll
        for (int off = 1; off < 64; off <<= 1) s1 += __shfl_xor(s1, off);

        float4 q = a;
        double sel = s1;
        int selc = c1;

        if (ta.z - ta.x < THR) {   // candidate 2 ambiguous (wave-uniform)
            int c2 = __float_as_int(ta.w);
            const float* w2 = wt + ((size_t)f * K + c2) * D;
            float4 b = ((const float4*)w2)[lane];
            double s2 = 0.0;
#pragma unroll
            for (int j = 0; j < 4; ++j) {
                double d2 = (double)((const float*)&xv)[j] - (double)((const float*)&b)[j];
                s2 = fma(d2, d2, s2);
            }
#pragma unroll
            for (int off = 1; off < 64; off <<= 1) s2 += __shfl_xor(s2, off);
            if ((s2 < sel) || (s2 == sel && c2 < selc)) { q = b; sel = s2; selc = c2; }
        }
        if (tb.x - ta.x < THR) {   // candidate 3 ambiguous (wave-uniform)
            int c3 = __float_as_int(tb.y);
            const float* w3 = wt + ((size_t)f * K + c3) * D;
            float4 b = ((const float4*)w3)[lane];
            double s3 = 0.0;
#pragma unroll
            for (int j = 0; j < 4; ++j) {
                double d3 = (double)((const float*)&xv)[j] - (double)((const float*)&b)[j];
                s3 = fma(d3, d3, s3);
            }
#pragma unroll
            for (int off = 1; off < 64; off <<= 1) s3 += __shfl_xor(s3, off);
            if ((s3 < sel) || (s3 == sel && c3 < selc)) { q = b; sel = s3; selc = c3; }
        }
        ((float4*)(out + row * D))[lane] = q;
        if (lane == 0) lsum += sel;
    }
    if (lane == 0) lpart[wv] = lsum;
    __syncthreads();
    if (tid == 0) {
        double tsum = lpart[0] + lpart[1] + lpart[2] + lpart[3];
        atomicAdd(lossAcc, tsum);
    }
}

__global__ void finish_loss(const double* __restrict__ lossAcc,
                            float* __restrict__ out_loss) {
    if (threadIdx.x == 0)
        *out_loss = (float)(0.25 * (*lossAcc) / ((double)F * (double)B * (double)D));
}

extern "C" void kernel_launch(void* const* d_in, const int* in_sizes, int n_in,
                              void* d_out, int out_size, void* d_ws, size_t ws_size,
                              hipStream_t stream) {
    const float* x = (const float*)d_in[0];   // [F,B,D]
    const float* w = (const float*)d_in[1];   // [F,D,K]
    float* out = (float*)d_out;

    ushort* whT   = (ushort*)((char*)d_ws + WHT_OFF);
    float*  wt    = (float*)((char*)d_ws + WT_OFF);
    float*  wsq   = (float*)((char*)d_ws + WSQ_OFF);
    float4* top3v = (float4*)((char*)d_ws + TOP3_OFF);
    double* lossAcc = (double*)((char*)d_ws + LOSS_OFF);

    transpose_w<<<dim3(K / 32, F), dim3(32, 8), 0, stream>>>(w, wt, whT, wsq, lossAcc);
    gemm_mfma_top3<<<dim3((B / 64) * F), 512, 0, stream>>>(x, whT, wsq, top3v);
    refine_gather<<<dim3(F * B / 64), 256, 0, stream>>>(x, wt, top3v, out, lossAcc);
    finish_loss<<<1, 64, 0, stream>>>(lossAcc, out + (size_t)F * B * D);
}

// Round 7
// 224.265 us; speedup vs baseline: 4.1076x; 1.0987x over previous
//
#include <hip/hip_runtime.h>
#include <cstdint>
#include <cfloat>

#define F 16
#define B 4096
#define D 256
#define K 1024

typedef __attribute__((ext_vector_type(8))) _Float16 f16x8;
typedef __attribute__((ext_vector_type(4))) float f32x4;

// ---- workspace layout (bytes) ----
#define WHT_OFF  0u            // F*K*D fp16 transposed [f][k][d] = 8388608
#define WT_OFF   8388608u      // F*K*D fp32 transposed = 16777216
#define WSQ_OFF  25165824u     // F*K fp32 = 65536
#define LOSS_OFF 25231360u

#define THR 0.012f             // refine ambiguity threshold (~13 sigma of fp16 GEMM err)

__device__ __forceinline__ void async_load16(const void* g, void* l) {
    __builtin_amdgcn_global_load_lds(
        (const __attribute__((address_space(1))) void*)g,
        (__attribute__((address_space(3))) void*)l, 16, 0, 0);
}

// merge two sorted top-3 lists (value asc, index tie-break asc) -> top-3
__device__ __forceinline__ void merge3(
        float& v1, int& i1, float& v2, int& i2, float& v3, int& i3,
        float w1, int j1, float w2, int j2, float w3, int j3)
{
    bool s = (w1 < v1) || (w1 == v1 && j1 < i1);
    float A1 = s ? w1 : v1; int A1i = s ? j1 : i1;
    float A2 = s ? w2 : v2; int A2i = s ? j2 : i2;
    float A3 = s ? w3 : v3; int A3i = s ? j3 : i3;
    float B1 = s ? v1 : w1; int B1i = s ? i1 : j1;
    float B2 = s ? v2 : w2; int B2i = s ? i2 : j2;
    bool t = (B1 < A2) || (B1 == A2 && B1i < A2i);
    float r2 = t ? B1 : A2; int r2i = t ? B1i : A2i;
    float c1 = t ? A2 : A3; int c1i = t ? A2i : A3i;
    float c2 = t ? B2 : B1; int c2i = t ? B2i : B1i;
    bool u = (c2 < c1) || (c2 == c1 && c2i < c1i);
    float r3 = u ? c2 : c1; int r3i = u ? c2i : c1i;
    v1 = A1; i1 = A1i; v2 = r2; i2 = r2i; v3 = r3; i3 = r3i;
}

// ------- transpose w -> wt fp32 [f][k][d] + fp16 + ||w_k||^2 (no atomics) -------
__global__ void transpose_w(const float* __restrict__ w, float* __restrict__ wt,
                            ushort* __restrict__ whT, float* __restrict__ wsq,
                            double* __restrict__ lossAcc) {
    __shared__ float sd[32][33];
    int f  = blockIdx.y;
    int k0 = blockIdx.x * 32;
    int tx = threadIdx.x, ty = threadIdx.y;
    if (f == 0 && blockIdx.x == 0 && tx == 0 && ty == 0) *lossAcc = 0.0;
    const float* wf = w + (size_t)f * D * K;
    size_t obase = (size_t)f * K * D;
    float ksum[4] = {0.f, 0.f, 0.f, 0.f};
    for (int d0 = 0; d0 < D; d0 += 32) {
        __syncthreads();
#pragma unroll
        for (int i = 0; i < 4; ++i) {
            int d = ty + i * 8;
            sd[d][tx] = wf[(size_t)(d0 + d) * K + (k0 + tx)];
        }
        __syncthreads();
#pragma unroll
        for (int i = 0; i < 4; ++i) {
            int k = ty + i * 8;
            float v = sd[tx][k];
            size_t o = obase + (size_t)(k0 + k) * D + (d0 + tx);
            wt[o] = v;
            _Float16 hv = (_Float16)v;
            whT[o] = *(ushort*)&hv;
            float p = v * v;
#pragma unroll
            for (int off = 1; off < 32; off <<= 1) p += __shfl_xor(p, off);
            if (tx == 0) ksum[i] += p;
        }
    }
    if (tx == 0) {
#pragma unroll
        for (int i = 0; i < 4; ++i)
            wsq[f * K + k0 + ty + i * 8] = ksum[i];
    }
}

// ---- MFMA fp16 GEMM + top-3 + FUSED fp64 refine/gather/loss ----
// Wave grid 4 row-groups x 2 col-groups: per wave 16 rows x 64 cols.
// A in 8 f16x8 regs. W staged 16 KB/stage, 4 LDS buffers, depth 3, vmcnt(4).
// Register contract (R1-R6): budget = 512/waves_per_eu TOTAL (VGPR+AGPR
// unified); at 4 waves/EU -> 128. Main loop ~100, epilogue less. No spill.
// T5 setprio(1) wraps the MFMA cluster (counted-vmcnt phase structure).
// Epilogue: block-level top-3 -> LDS; each wave refines 8 rows with exact
// fp64 distances (x re-read L2-hot, wt gather L2-hot), writes out + loss.
__global__ __launch_bounds__(512) __attribute__((amdgpu_waves_per_eu(4)))
void gemm_mfma_top3(
        const float* __restrict__ x, const ushort* __restrict__ whT,
        const float* __restrict__ wsq, const float* __restrict__ wt,
        float* __restrict__ out, double* __restrict__ lossAcc)
{
    __shared__ __align__(16) ushort lds[34816];
    const int bid  = blockIdx.x;
    const int f    = bid >> 6;             // 64 consecutive blocks share f (W L2-hot)
    const int m0   = (bid & 63) * 64;
    const int tid  = threadIdx.x;
    const int lane = tid & 63;
    const int wave = tid >> 6;             // 0..7
    const int rw   = wave >> 1;            // 0..3 : 16-row group
    const int cw   = wave & 1;             // 0..1 : 64-col half of the 128-chunk
    const int quad = lane >> 4, l15 = lane & 15;

    const ushort* whb = whT + (size_t)f * K * D;
    const int col_ = tid & 127;            // staging col within chunk
    const int sg_  = tid >> 7;             // staging d-octet 0..3
    const ushort* wsrc = whb + (size_t)col_ * D + sg_ * 8;

    // ---- DMAs first: wsq slab + W stages 0,1,2 (depth 3)
    if (tid < 256) async_load16(wsq + f * K + tid * 4, &lds[32768 + tid * 8]);
#pragma unroll
    for (int p = 0; p < 3; ++p) {
        async_load16(wsrc + p * 64,      &lds[p * 8192 + tid * 8]);
        async_load16(wsrc + p * 64 + 32, &lds[p * 8192 + 4096 + tid * 8]);
    }

    // ---- A into registers: a[ks] = row rw*16+l15, d = ks*32 + quad*8 .. +8
    const float* xb = x + ((size_t)f * B + m0) * D;
    f16x8 a[8];
#pragma unroll
    for (int ks = 0; ks < 8; ++ks) {
        const float* src = xb + (size_t)(rw * 16 + l15) * D + ks * 32 + quad * 8;
        float4 u0 = *(const float4*)src;
        float4 u1 = *(const float4*)(src + 4);
        f16x8 h;
        h[0] = (_Float16)u0.x; h[1] = (_Float16)u0.y;
        h[2] = (_Float16)u0.z; h[3] = (_Float16)u0.w;
        h[4] = (_Float16)u1.x; h[5] = (_Float16)u1.y;
        h[6] = (_Float16)u1.z; h[7] = (_Float16)u1.w;
        a[ks] = h;
    }

    asm volatile("s_waitcnt vmcnt(0)" ::: "memory");   // A + prologue DMAs done
    __builtin_amdgcn_s_barrier();

    float v1[4], v2[4];
    unsigned int ii[4];                    // i1 | (i2<<16)
#pragma unroll
    for (int s = 0; s < 4; ++s) { v1[s] = FLT_MAX; v2[s] = FLT_MAX; ii[s] = 0xFFFFFFFFu; }

    const float* wsql = (const float*)(&lds[32768]);

#pragma unroll 1
    for (int c = 0; c < 8; ++c) {
        f32x4 acc[4];
#pragma unroll
        for (int nt = 0; nt < 4; ++nt) acc[nt] = (f32x4){0.f, 0.f, 0.f, 0.f};

#pragma unroll
        for (int sl = 0; sl < 4; ++sl) {
            const int s = c * 4 + sl;
            // stage-s loads (issued 3 stages ago) complete; 2 newer pairs stay
            asm volatile("s_waitcnt vmcnt(4)" ::: "memory");
            __builtin_amdgcn_s_barrier();
            // prefetch stage s+3 into buffer freed at this barrier ((sl-1)&3)
            int sp = s + 3; if (sp > 31) sp = 31;   // tail: harmless dummy reloads
            const ushort* gsrc = wsrc + (size_t)(sp >> 2) * (128 * D) + (sp & 3) * 64;
            const int db = ((sl + 3) & 3) * 8192;
            async_load16(gsrc,      &lds[db + tid * 8]);
            async_load16(gsrc + 32, &lds[db + 4096 + tid * 8]);

            const ushort* wb = &lds[sl * 8192];
#pragma unroll
            for (int kk = 0; kk < 2; ++kk) {
                const int ks = sl * 2 + kk;
                const int kb = (kk * 4 + quad) * 1024;
                f16x8 b0 = *(const f16x8*)(&wb[kb + (cw * 64 +  0 + l15) * 8]);
                f16x8 b1 = *(const f16x8*)(&wb[kb + (cw * 64 + 16 + l15) * 8]);
                f16x8 b2 = *(const f16x8*)(&wb[kb + (cw * 64 + 32 + l15) * 8]);
                f16x8 b3 = *(const f16x8*)(&wb[kb + (cw * 64 + 48 + l15) * 8]);
                __builtin_amdgcn_s_setprio(1);
                acc[0] = __builtin_amdgcn_mfma_f32_16x16x32_f16(a[ks], b0, acc[0], 0, 0, 0);
                acc[1] = __builtin_amdgcn_mfma_f32_16x16x32_f16(a[ks], b1, acc[1], 0, 0, 0);
                acc[2] = __builtin_amdgcn_mfma_f32_16x16x32_f16(a[ks], b2, acc[2], 0, 0, 0);
                acc[3] = __builtin_amdgcn_mfma_f32_16x16x32_f16(a[ks], b3, acc[3], 0, 0, 0);
                __builtin_amdgcn_s_setprio(0);
            }
        }

        // epilogue: fold this 128-col chunk into per-lane top-2 (4 row-slots)
#pragma unroll
        for (int nt = 0; nt < 4; ++nt) {
            int ng = c * 128 + cw * 64 + nt * 16 + l15;
            float wq = wsql[ng];
#pragma unroll
            for (int r = 0; r < 4; ++r) {
                float sc = fmaf(-2.f, acc[nt][r], wq);
                bool lt1 = sc < v1[r];
                bool lt2 = sc < v2[r];
                unsigned int lo = ii[r] & 0xFFFFu;
                unsigned int cpush = (lo << 16) | (unsigned int)ng;
                unsigned int crep  = lo | ((unsigned int)ng << 16);
                ii[r] = lt1 ? cpush : (lt2 ? crep : ii[r]);
                v2[r] = lt1 ? v1[r] : (lt2 ? sc : v2[r]);
                v1[r] = lt1 ? sc : v1[r];
            }
        }
    }

    asm volatile("s_waitcnt vmcnt(0)" ::: "memory");   // drain tail dummy DMAs
    __syncthreads();

    // unpack, extend to top-3, butterfly-merge among the 16 l15 lanes
    float v3[4]; int i1[4], i2[4], i3[4];
#pragma unroll
    for (int s = 0; s < 4; ++s) {
        i1[s] = (int)(ii[s] & 0xFFFFu);
        i2[s] = (int)(ii[s] >> 16);
        v3[s] = FLT_MAX; i3[s] = 0x7fffffff;
    }
#pragma unroll
    for (int s = 0; s < 4; ++s) {
#pragma unroll
        for (int off = 1; off < 16; off <<= 1) {
            float w1 = __shfl_xor(v1[s], off); int j1 = __shfl_xor(i1[s], off);
            float w2 = __shfl_xor(v2[s], off); int j2 = __shfl_xor(i2[s], off);
            float w3 = __shfl_xor(v3[s], off); int j3 = __shfl_xor(i3[s], off);
            merge3(v1[s], i1[s], v2[s], i2[s], v3[s], i3[s], w1, j1, w2, j2, w3, j3);
        }
    }

    // cross-wave (cw 0..1) partials -> LDS: [64 rows][2 cw][2 float4]
    float4* mrg = (float4*)lds;
    if (l15 == 0) {
#pragma unroll
        for (int r = 0; r < 4; ++r) {
            int rl = rw * 16 + quad * 4 + r;
            mrg[(rl * 2 + cw) * 2 + 0] = make_float4(v1[r], __int_as_float(i1[r]),
                                                     v2[r], __int_as_float(i2[r]));
            mrg[(rl * 2 + cw) * 2 + 1] = make_float4(v3[r], __int_as_float(i3[r]), 0.f, 0.f);
        }
    }
    __syncthreads();
    // final merged top-3 per row -> mrg2 (float4 idx 256..383)
    float4* mrg2 = ((float4*)lds) + 256;
    if (cw == 0 && l15 == 0) {
#pragma unroll
        for (int r = 0; r < 4; ++r) {
            int rl = rw * 16 + quad * 4 + r;
            float4 ta = mrg[(rl * 2 + 0) * 2 + 0];
            float4 tb = mrg[(rl * 2 + 0) * 2 + 1];
            float bv1 = ta.x, bv2 = ta.z, bv3 = tb.x;
            int   bi1 = __float_as_int(ta.y), bi2 = __float_as_int(ta.w),
                  bi3 = __float_as_int(tb.y);
            float4 oa = mrg[(rl * 2 + 1) * 2 + 0];
            float4 ob = mrg[(rl * 2 + 1) * 2 + 1];
            merge3(bv1, bi1, bv2, bi2, bv3, bi3,
                   oa.x, __float_as_int(oa.y), oa.z, __float_as_int(oa.w),
                   ob.x, __float_as_int(ob.y));
            mrg2[rl * 2 + 0] = make_float4(bv1, __int_as_float(bi1),
                                           bv2, __int_as_float(bi2));
            mrg2[rl * 2 + 1] = make_float4(bv3, __int_as_float(bi3), 0.f, 0.f);
        }
    }
    __syncthreads();

    // ---- fused fp64 refine + gather + loss: wave handles rows wave*8..+7
    double lsum = 0.0;
    for (int it = 0; it < 8; ++it) {
        int rl = wave * 8 + it;
        float4 t0 = mrg2[rl * 2 + 0];
        float4 t1 = mrg2[rl * 2 + 1];
        int c1 = __float_as_int(t0.y);
        const float* xr = xb + (size_t)rl * D;       // L2-hot (read in prologue)
        float4 xv = ((const float4*)xr)[lane];

        const float* w1 = wt + ((size_t)f * K + c1) * D;
        float4 ar = ((const float4*)w1)[lane];
        double s1 = 0.0;
#pragma unroll
        for (int j = 0; j < 4; ++j) {
            double d1 = (double)((const float*)&xv)[j] - (double)((const float*)&ar)[j];
            s1 = fma(d1, d1, s1);
        }
#pragma unroll
        for (int off = 1; off < 64; off <<= 1) s1 += __shfl_xor(s1, off);

        float4 q = ar;
        double sel = s1;
        int selc = c1;

        if (t0.z - t0.x < THR) {   // candidate 2 ambiguous (wave-uniform)
            int c2 = __float_as_int(t0.w);
            const float* w2 = wt + ((size_t)f * K + c2) * D;
            float4 br = ((const float4*)w2)[lane];
            double s2 = 0.0;
#pragma unroll
            for (int j = 0; j < 4; ++j) {
                double d2 = (double)((const float*)&xv)[j] - (double)((const float*)&br)[j];
                s2 = fma(d2, d2, s2);
            }
#pragma unroll
            for (int off = 1; off < 64; off <<= 1) s2 += __shfl_xor(s2, off);
            if ((s2 < sel) || (s2 == sel && c2 < selc)) { q = br; sel = s2; selc = c2; }
        }
        if (t1.x - t0.x < THR) {   // candidate 3 ambiguous (wave-uniform)
            int c3 = __float_as_int(t1.y);
            const float* w3 = wt + ((size_t)f * K + c3) * D;
            float4 br = ((const float4*)w3)[lane];
            double s3 = 0.0;
#pragma unroll
            for (int j = 0; j < 4; ++j) {
                double d3 = (double)((const float*)&xv)[j] - (double)((const float*)&br)[j];
                s3 = fma(d3, d3, s3);
            }
#pragma unroll
            for (int off = 1; off < 64; off <<= 1) s3 += __shfl_xor(s3, off);
            if ((s3 < sel) || (s3 == sel && c3 < selc)) { q = br; sel = s3; selc = c3; }
        }
        ((float4*)(out + ((size_t)f * B + m0 + rl) * D))[lane] = q;
        if (lane == 0) lsum += sel;
    }

    // block loss reduction -> one atomic
    __syncthreads();                        // mrg2 reads done; reuse LDS
    double* lp = (double*)lds;
    if (lane == 0) lp[wave] = lsum;
    __syncthreads();
    if (tid == 0) {
        double t = lp[0] + lp[1] + lp[2] + lp[3] + lp[4] + lp[5] + lp[6] + lp[7];
        atomicAdd(lossAcc, t);
    }
}

__global__ void finish_loss(const double* __restrict__ lossAcc,
                            float* __restrict__ out_loss) {
    if (threadIdx.x == 0)
        *out_loss = (float)(0.25 * (*lossAcc) / ((double)F * (double)B * (double)D));
}

extern "C" void kernel_launch(void* const* d_in, const int* in_sizes, int n_in,
                              void* d_out, int out_size, void* d_ws, size_t ws_size,
                              hipStream_t stream) {
    const float* x = (const float*)d_in[0];   // [F,B,D]
    const float* w = (const float*)d_in[1];   // [F,D,K]
    float* out = (float*)d_out;

    ushort* whT   = (ushort*)((char*)d_ws + WHT_OFF);
    float*  wt    = (float*)((char*)d_ws + WT_OFF);
    float*  wsq   = (float*)((char*)d_ws + WSQ_OFF);
    double* lossAcc = (double*)((char*)d_ws + LOSS_OFF);

    transpose_w<<<dim3(K / 32, F), dim3(32, 8), 0, stream>>>(w, wt, whT, wsq, lossAcc);
    gemm_mfma_top3<<<dim3((B / 64) * F), 512, 0, stream>>>(x, whT, wsq, wt, out, lossAcc);
    finish_loss<<<1, 64, 0, stream>>>(lossAcc, out + (size_t)F * B * D);
}